// Round 8
// baseline (1237.498 us; speedup 1.0000x reference)
//
#include <hip/hip_runtime.h>
#include <hip/hip_bf16.h>
#include <math.h>

#define S 512
#define B 8
#define H 768
#define NH 12
#define DH 64
#define DV 192
#define II 2304
#define NL 4
#define SCALE 0.07216878364870322f
#define EPS 1e-7f

#define NW0 (2*II*H)   // Wv elems  3,538,944
#define NW1 (2*H*H)    // Wqk elems 1,179,648
#define NW2 (H*II)     // Wo elems  1,769,472

typedef __attribute__((ext_vector_type(8))) short short8;
typedef __attribute__((ext_vector_type(4))) float f32x4;

__device__ __forceinline__ float b2f(ushort u){
  union { float f; unsigned int u; } v; v.u = ((unsigned int)u) << 16; return v.f;
}
__device__ __forceinline__ ushort f2b(float f){
  union { float f; unsigned int u; } v; v.f = f;
  unsigned int u = v.u;
  return (ushort)((u + 0x7fffu + ((u >> 16) & 1u)) >> 16);
}
__device__ __forceinline__ float gelu_f(float x){
  return 0.5f * x * (1.0f + erff(x * 0.70710678118654752f));
}
// async global(16B/lane) -> LDS (wave-uniform base + lane*16)
__device__ __forceinline__ void async_copy16(const ushort* g, ushort* l){
  __builtin_amdgcn_global_load_lds(
      (const __attribute__((address_space(1))) void*)g,
      (__attribute__((address_space(3))) void*)l, 16, 0, 0);
}

// ---- block-wide sum of two floats across 256 threads (4 waves) ----
__device__ __forceinline__ void block_sum2(float& s, float& s2, float* red, int t){
  #pragma unroll
  for(int off=32; off>=1; off>>=1){ s += __shfl_xor(s, off); s2 += __shfl_xor(s2, off); }
  int w = t >> 6;
  if((t & 63) == 0){ red[w] = s; red[4 + w] = s2; }
  __syncthreads();
  s  = red[0] + red[1] + red[2] + red[3];
  s2 = red[4] + red[5] + red[6] + red[7];
}

// ---- fused f32->bf16 convert of Wv|Wqk|Wo into one contiguous bf16 buffer ----
__global__ __launch_bounds__(256)
void f2b3_kernel(const float* __restrict__ in0, const float* __restrict__ in1,
                 const float* __restrict__ in2, ushort* __restrict__ out){
  int i = (blockIdx.x * 256 + threadIdx.x) * 4;
  const float* src; int off;
  if(i < NW0){ src = in0; off = i; }
  else if(i < NW0+NW1){ src = in1; off = i - NW0; }
  else { src = in2; off = i - NW0 - NW1; }
  float4 v = *(const float4*)(src + off);
  __attribute__((aligned(8))) ushort tmp[4] = { f2b(v.x), f2b(v.y), f2b(v.z), f2b(v.w) };
  *(uint2*)(out + i) = *(const uint2*)tmp;
}

// ---- x = LN(word_emb[ids])  (f32 in, f32 out) ----
__global__ __launch_bounds__(256)
void embed_ln_kernel(const int* __restrict__ ids, const float* __restrict__ wemb,
                     float* __restrict__ x)
{
  __shared__ float red[8];
  const int sb = blockIdx.x, t = threadIdx.x;
  const float* row = wemb + (size_t)ids[sb] * H;
  float v0 = row[t], v1 = row[t+256], v2 = row[t+512];
  float s = v0+v1+v2, s2 = v0*v0+v1*v1+v2*v2;
  block_sum2(s, s2, red, t);
  float mean = s * (1.0f/H);
  float rstd = rsqrtf(s2*(1.0f/H) - mean*mean + EPS);
  float* xo = x + (size_t)sb * H;
  xo[t]     = (v0-mean)*rstd;
  xo[t+256] = (v1-mean)*rstd;
  xo[t+512] = (v2-mean)*rstd;
}

// ---- relb = LN(rel_emb)*w + b  (f32 in, bf16 out) ----
__global__ __launch_bounds__(256)
void rel_ln_kernel(const float* __restrict__ rel_emb, const float* __restrict__ w,
                   const float* __restrict__ bia, ushort* __restrict__ outb)
{
  __shared__ float red[8];
  const int j = blockIdx.x, t = threadIdx.x;
  const float* row = rel_emb + (size_t)j * H;
  float v0=row[t], v1=row[t+256], v2=row[t+512];
  float s=v0+v1+v2, s2=v0*v0+v1*v1+v2*v2;
  block_sum2(s,s2,red,t);
  float mean = s*(1.0f/H);
  float rstd = rsqrtf(s2*(1.0f/H)-mean*mean+EPS);
  ushort* o = outb + (size_t)j*H;
  o[t]     = f2b((v0-mean)*rstd * w[t]     + bia[t]);
  o[t+256] = f2b((v1-mean)*rstd * w[t+256] + bia[t+256]);
  o[t+512] = f2b((v2-mean)*rstd * w[t+512] + bia[t+512]);
}

// ---- h = LN(x)  (bf16 out) ----
__global__ __launch_bounds__(256)
void ln_x_kernel(const float* __restrict__ x, ushort* __restrict__ h)
{
  __shared__ float red[8];
  const int sb = blockIdx.x, t = threadIdx.x;
  const float* row = x + (size_t)sb * H;
  float v0 = row[t], v1 = row[t+256], v2 = row[t+512];
  float s = v0+v1+v2, s2 = v0*v0+v1*v1+v2*v2;
  block_sum2(s, s2, red, t);
  float mean = s * (1.0f/H);
  float rstd = rsqrtf(s2*(1.0f/H) - mean*mean + EPS);
  ushort* o = h + (size_t)sb * H;
  o[t]     = f2b((v0-mean)*rstd);
  o[t+256] = f2b((v1-mean)*rstd);
  o[t+512] = f2b((v2-mean)*rstd);
}

// ---- bucket table: pidx depends only on (q-k); sample row 0 / row 511 ----
__global__ __launch_bounds__(256)
void bucket_kernel(const int* __restrict__ pidx, unsigned char* __restrict__ buk){
  int r = blockIdx.x*256 + threadIdx.x;   // [0,1024)
  int rel = r - 511;
  int v = 0;
  if(rel <= 0)          v = pidx[-rel];               // row 0, col -rel
  else if(rel <= 511)   v = pidx[511*S + (511-rel)];  // row 511
  buk[r] = (unsigned char)v;
}

// ---- small GEMM (64x64 tile): pos = relb @ Wqk^T + bqk (M=63) ----
__global__ __launch_bounds__(256)
void gemm_nt64(const ushort* __restrict__ A, const ushort* __restrict__ Bw,
               const float* __restrict__ bias, ushort* __restrict__ Cout,
               int M, int N, int K)
{
  __shared__ ushort As[64][40];
  __shared__ ushort Bs[64][40];
  const int n0 = blockIdx.x * 64, m0 = blockIdx.y * 64;
  const int t = threadIdx.x;
  const int lrow = t >> 2, lk = (t & 3) * 8;
  const int lane = t & 63, w = t >> 6, lr = lane & 15, lq = lane >> 4;
  const int wr = (w >> 1) * 32, wc = (w & 1) * 32;
  f32x4 z = {0.f,0.f,0.f,0.f};
  f32x4 acc[2][2] = {{z,z},{z,z}};
  const int arow = m0 + lrow;
  const ushort* aptr = A  + (size_t)arow * K + lk;
  const ushort* bptr = Bw + (size_t)(n0 + lrow) * K + lk;
  for(int k0 = 0; k0 < K; k0 += 32){
    short8 av = {0,0,0,0,0,0,0,0};
    if(arow < M) av = *(const short8*)(aptr + k0);
    short8 bv = *(const short8*)(bptr + k0);
    __syncthreads();
    *(short8*)&As[lrow][lk] = av;
    *(short8*)&Bs[lrow][lk] = bv;
    __syncthreads();
    short8 a0 = *(const short8*)&As[wr + lr][lq * 8];
    short8 a1 = *(const short8*)&As[wr + 16 + lr][lq * 8];
    short8 b0 = *(const short8*)&Bs[wc + lr][lq * 8];
    short8 b1 = *(const short8*)&Bs[wc + 16 + lr][lq * 8];
    acc[0][0] = __builtin_amdgcn_mfma_f32_16x16x32_bf16(a0, b0, acc[0][0], 0,0,0);
    acc[0][1] = __builtin_amdgcn_mfma_f32_16x16x32_bf16(a0, b1, acc[0][1], 0,0,0);
    acc[1][0] = __builtin_amdgcn_mfma_f32_16x16x32_bf16(a1, b0, acc[1][0], 0,0,0);
    acc[1][1] = __builtin_amdgcn_mfma_f32_16x16x32_bf16(a1, b1, acc[1][1], 0,0,0);
  }
  #pragma unroll
  for(int i=0;i<2;i++){
    #pragma unroll
    for(int j=0;j<2;j++){
      #pragma unroll
      for(int r=0;r<4;r++){
        int m = m0 + wr + i*16 + lq*4 + r;
        int n = n0 + wc + j*16 + lr;
        if(m >= M) continue;
        float v = acc[i][j][r];
        if(bias) v += bias[n];
        Cout[(size_t)m*N + n] = f2b(v);
      }
    }
  }
}

// ---- main GEMM: 128x128 tile, BK=64 (two 32-col LDS slabs) ----
// OUT_MODE: 0 = f32 store, 1 = bf16 store, 2 = f32 accumulate (+=)
template<int OUT_MODE>
__global__ __launch_bounds__(256)
void gemm128(const ushort* __restrict__ A, const ushort* __restrict__ Bw,
             const float* __restrict__ bias, void* __restrict__ Cout,
             int M, int N, int K)
{
  __shared__ ushort As[2][128*32];
  __shared__ ushort Bs[2][128*32];
  const int t = threadIdx.x, w = t>>6, lane = t&63, lr = lane&15, lq = lane>>4;
  const int m0 = blockIdx.y*128, n0 = blockIdx.x*128;
  const int wr = (w>>1)*64, wc = (w&1)*64;
  const int srow = (w*2)*16 + (lane>>2);
  const int sk = (lane&3)*8;
  const ushort* aG = A  + (size_t)(m0+srow)*K + sk;
  const ushort* bG = Bw + (size_t)(n0+srow)*K + sk;
  f32x4 z = {0.f,0.f,0.f,0.f};
  f32x4 acc[4][4] = {{z,z,z,z},{z,z,z,z},{z,z,z,z},{z,z,z,z}};
  for(int k0 = 0; k0 < K; k0 += 64){
    __syncthreads();
    #pragma unroll
    for(int s=0;s<2;s++){
      async_copy16(aG + k0 + s*32,                 As[s] + (w*2)*512);
      async_copy16(aG + k0 + s*32 + (size_t)16*K,  As[s] + (w*2+1)*512);
      async_copy16(bG + k0 + s*32,                 Bs[s] + (w*2)*512);
      async_copy16(bG + k0 + s*32 + (size_t)16*K,  Bs[s] + (w*2+1)*512);
    }
    __syncthreads();
    #pragma unroll
    for(int s=0;s<2;s++){
      short8 af[4], bf[4];
      #pragma unroll
      for(int i=0;i<4;i++) af[i] = *(const short8*)&As[s][(wr + i*16 + lr)*32 + lq*8];
      #pragma unroll
      for(int j=0;j<4;j++) bf[j] = *(const short8*)&Bs[s][(wc + j*16 + lr)*32 + lq*8];
      #pragma unroll
      for(int i=0;i<4;i++)
        #pragma unroll
        for(int j=0;j<4;j++)
          acc[i][j] = __builtin_amdgcn_mfma_f32_16x16x32_bf16(af[i], bf[j], acc[i][j], 0,0,0);
    }
  }
  #pragma unroll
  for(int i=0;i<4;i++){
    #pragma unroll
    for(int j=0;j<4;j++){
      #pragma unroll
      for(int r=0;r<4;r++){
        int m = m0 + wr + i*16 + lq*4 + r;
        int n = n0 + wc + j*16 + lr;
        float v = acc[i][j][r];
        if(bias) v += bias[n];
        if(OUT_MODE == 0)      ((float*) Cout)[(size_t)m*N + n] = v;
        else if(OUT_MODE == 1) ((ushort*)Cout)[(size_t)m*N + n] = f2b(v);
        else                   ((float*) Cout)[(size_t)m*N + n] += v;
      }
    }
  }
}

// ---- pipelined vg+qk GEMM: tile 128x256, BK=64, 512 threads (8 waves 2Mx4N).
// THREE SEPARATE __shared__ buffers + statically-unrolled x3 K-loop so every
// tile's current/stage buffers are compile-time-named objects. This lets the
// waitcnt pass disambiguate ds_reads from in-flight global_load_lds (rotating
// pointers into one object forced conservative vmcnt(0) waits -> serialized
// pipeline, 503 TF). Schedule (counted vmcnt(6), 2-ahead staging, XOR swizzle,
// setprio, sched_barrier fences) is unchanged. ----
#define VGQK_TILE(KT, CUR, SB) do {                                            \
    const int ks0_ = ((KT)+2)*64;                                              \
    const bool do_stage_ = ((KT)+2) < NT;                                      \
    if((KT) < NT-1) asm volatile("s_waitcnt vmcnt(6)" ::: "memory");           \
    else            asm volatile("s_waitcnt vmcnt(0)" ::: "memory");           \
    __builtin_amdgcn_s_barrier();                                              \
    __builtin_amdgcn_sched_barrier(0);                                         \
    short8 bfr_[4][2], afr_[2][2];                                             \
    _Pragma("unroll")                                                          \
    for(int j=0;j<4;j++)                                                       \
      _Pragma("unroll")                                                        \
      for(int ks=0;ks<2;ks++)                                                  \
        bfr_[j][ks] = *(const short8*)&(CUR)[8192 + (wn*64 + j*16 + lr)*64 + ((ks*32 + lq*8) ^ rxor)]; \
    _Pragma("unroll")                                                          \
    for(int i=0;i<2;i++)                                                       \
      _Pragma("unroll")                                                        \
      for(int ks=0;ks<2;ks++)                                                  \
        afr_[i][ks] = *(const short8*)&(CUR)[(wm*64 + i*16 + lr)*64 + ((ks*32 + lq*8) ^ rxor)]; \
    if(do_stage_){                                                             \
      async_copy16(aSrc + ks0_,                (SB) + dA);                     \
      async_copy16(aSrc + (size_t)64*K + ks0_, (SB) + 4096 + dA);              \
      async_copy16(bSrc + ks0_,                (SB) + 8192 + dA);              \
    }                                                                          \
    __builtin_amdgcn_s_barrier();                                              \
    asm volatile("s_waitcnt lgkmcnt(0)" ::: "memory");                         \
    __builtin_amdgcn_sched_barrier(0);                                         \
    __builtin_amdgcn_s_setprio(1);                                             \
    _Pragma("unroll")                                                          \
    for(int i=0;i<2;i++)                                                       \
      _Pragma("unroll")                                                        \
      for(int j=0;j<4;j++)                                                     \
        _Pragma("unroll")                                                      \
        for(int ks=0;ks<2;ks++)                                                \
          acc[i][j] = __builtin_amdgcn_mfma_f32_16x16x32_bf16(afr_[i][ks], bfr_[j][ks], acc[i][j], 0,0,0); \
    __builtin_amdgcn_s_setprio(0);                                             \
    __builtin_amdgcn_s_barrier();                                              \
    __builtin_amdgcn_sched_barrier(0);                                         \
    short8 afr2_[2][2];                                                        \
    _Pragma("unroll")                                                          \
    for(int i=0;i<2;i++)                                                       \
      _Pragma("unroll")                                                        \
      for(int ks=0;ks<2;ks++)                                                  \
        afr2_[i][ks] = *(const short8*)&(CUR)[(wm*64 + (2+i)*16 + lr)*64 + ((ks*32 + lq*8) ^ rxor)]; \
    if(do_stage_){                                                             \
      async_copy16(bSrc + (size_t)64*K + ks0_,  (SB) + 12288 + dA);            \
      async_copy16(bSrc + (size_t)128*K + ks0_, (SB) + 16384 + dA);            \
      async_copy16(bSrc + (size_t)192*K + ks0_, (SB) + 20480 + dA);            \
    }                                                                          \
    __builtin_amdgcn_s_barrier();                                              \
    asm volatile("s_waitcnt lgkmcnt(0)" ::: "memory");                         \
    __builtin_amdgcn_sched_barrier(0);                                         \
    __builtin_amdgcn_s_setprio(1);                                             \
    _Pragma("unroll")                                                          \
    for(int i=0;i<2;i++)                                                       \
      _Pragma("unroll")                                                        \
      for(int j=0;j<4;j++)                                                     \
        _Pragma("unroll")                                                      \
        for(int ks=0;ks<2;ks++)                                                \
          acc[2+i][j] = __builtin_amdgcn_mfma_f32_16x16x32_bf16(afr2_[i][ks], bfr_[j][ks], acc[2+i][j], 0,0,0); \
    __builtin_amdgcn_s_setprio(0);                                             \
  } while(0)

__global__ __launch_bounds__(512)
void gemm_vgqk8(const ushort* __restrict__ A, const ushort* __restrict__ Ww,
                const float* __restrict__ bqk, ushort* __restrict__ vg,
                ushort* __restrict__ qk)
{
  constexpr int K  = H;        // 768
  constexpr int NT = K / 64;   // 12 k-tiles (multiple of 3)
  // per buffer: A[128 rows][64 cols] @ 0 (8192 ushorts), B[256 rows][64] @ 8192
  __shared__ ushort buf0[24576];     // 3 x 48KB = 144KB (gfx950 LDS = 160KB)
  __shared__ ushort buf1[24576];
  __shared__ ushort buf2[24576];
  const int t = threadIdx.x;
  const int w = t >> 6, l = t & 63, lr = l & 15, lq = l >> 4;
  const int wm = w >> 2, wn = w & 3;
  // bijective XCD swizzle: 768 blocks = 8 XCDs x 96; chunk covers 3 B-panels x all 32 m
  int id = blockIdx.x;
  int swz = (id & 7) * 96 + (id >> 3);
  const int bm = swz & 31, bn = swz >> 5;     // 32 m-blocks, 24 n-blocks
  const int m0 = bm * 128, n0 = bn * 256;

  // staging: each gload_lds = 8KB (512 thr x 16B) = 64 rows; lane l covers
  // row (l>>3), 16B-chunk (l&7). LDS dest is linear; SOURCE col pre-swizzled
  // with the same involution the reads use: chunk' = chunk ^ (row&7).
  const int srow = l >> 3;
  const int scol = ((l & 7) ^ srow) << 3;     // ushort units
  const ushort* aSrc = A  + (size_t)(m0 + w*8 + srow) * K + scol;
  const ushort* bSrc = Ww + (size_t)(n0 + w*8 + srow) * K + scol;
  const int dA = w * 512;                     // wave's 1KB slot within a 64-row step
  const int rxor = (lr & 7) << 3;             // read-side swizzle (ushort units)

  f32x4 z = {0.f,0.f,0.f,0.f};
  f32x4 acc[4][4] = {{z,z,z,z},{z,z,z,z},{z,z,z,z},{z,z,z,z}};

  // prologue: stage k-tile 0 -> buf0, k-tile 1 -> buf1 (static buffers,
  // per-tile order matches the in-loop order: A0,A1,B0 | B1,B2,B3)
  async_copy16(aSrc + 0,                  buf0 + dA);
  async_copy16(aSrc + (size_t)64*K + 0,   buf0 + 4096  + dA);
  async_copy16(bSrc + 0,                  buf0 + 8192  + dA);
  async_copy16(bSrc + (size_t)64*K + 0,   buf0 + 12288 + dA);
  async_copy16(bSrc + (size_t)128*K + 0,  buf0 + 16384 + dA);
  async_copy16(bSrc + (size_t)192*K + 0,  buf0 + 20480 + dA);
  async_copy16(aSrc + 64,                 buf1 + dA);
  async_copy16(aSrc + (size_t)64*K + 64,  buf1 + 4096  + dA);
  async_copy16(bSrc + 64,                 buf1 + 8192  + dA);
  async_copy16(bSrc + (size_t)64*K + 64,  buf1 + 12288 + dA);
  async_copy16(bSrc + (size_t)128*K + 64, buf1 + 16384 + dA);
  async_copy16(bSrc + (size_t)192*K + 64, buf1 + 20480 + dA);

  // K-loop: 4 macro-iterations x 3 tiles with statically-rotated buffers.
  // tile kt reads buf[kt%3], stages kt+2 into buf[(kt+2)%3].
  for(int m3=0; m3<NT/3; m3++){
    const int kt = m3*3;
    VGQK_TILE(kt,   buf0, buf2);
    VGQK_TILE(kt+1, buf1, buf0);
    VGQK_TILE(kt+2, buf2, buf1);
  }

  const bool is_qk = (n0 >= 2*II);
  #pragma unroll
  for(int i=0;i<4;i++){
    #pragma unroll
    for(int j=0;j<4;j++){
      #pragma unroll
      for(int r=0;r<4;r++){
        int m = m0 + wm*64 + i*16 + lq*4 + r;
        int n = n0 + wn*64 + j*16 + lr;
        float v = acc[i][j][r];
        if(is_qk){
          int nq = n - 2*II;
          qk[(size_t)m*(2*H) + nq] = f2b(v + bqk[nq]);
        } else {
          vg[(size_t)m*(2*II) + n] = f2b(v);
        }
      }
    }
  }
}

// ---- merged: Vt transpose (blocks [0,1536)) + cp/cq MFMA ([1536,2304))
//      + K transpose ([2304,2400)): kT[bh][s][64] for coalesced attn K reads ----
__global__ __launch_bounds__(256)
void vtcpq_kernel(const ushort* __restrict__ vg, ushort* __restrict__ vt,
                  const ushort* __restrict__ qk, const ushort* __restrict__ posb,
                  ushort* __restrict__ cpT, ushort* __restrict__ cqT,
                  ushort* __restrict__ kT)
{
  const int id = blockIdx.x;
  const int t = threadIdx.x;
  __shared__ ushort tile[32][200];
  if(id < 1536){
    const int st = id & 15;
    const int hh = (id >> 4) % 12;
    const int b  = id / 192;
    {
      int sl = t >> 3, v0 = (t & 7) * 24;
      const ushort* src = vg + ((size_t)((st*32 + sl)*B + b))*(2*II) + hh*DV + v0;
      *(short8*)&tile[sl][v0]      = *(const short8*)(src);
      *(short8*)&tile[sl][v0 + 8]  = *(const short8*)(src + 8);
      *(short8*)&tile[sl][v0 + 16] = *(const short8*)(src + 16);
    }
    __syncthreads();
    if(t < DV){
      __attribute__((aligned(16))) ushort tmp[32];
      #pragma unroll
      for(int s2=0;s2<32;s2++) tmp[s2] = tile[s2][t];
      // k-slab-major layout: vt[((bh*16 + st)*DV + v)*32 + c]  (fully coalesced)
      ushort* dst = vt + ((((size_t)(b*NH + hh))*16 + st)*DV + t)*32;
      #pragma unroll
      for(int c=0;c<32;c+=8) *(short8*)(dst + c) = *(const short8*)&tmp[c];
    }
  } else if(id < 2304){
    const int jid = id - 1536;
    const int kc = jid & 3;
    const int bh = (jid >> 2) % 96;
    const int which = jid / 384;
    const int bb = bh / NH, h = bh - bb*NH;
    const int w = t>>6, lane = t&63, lr = lane&15, lq = lane>>4;
    const ushort* ab = posb + (size_t)(w*16 + lr)*1536 + (which ? 0 : 768) + h*64;
    short8 a0 = *(const short8*)(ab + lq*8);
    short8 a1 = *(const short8*)(ab + 32 + lq*8);
    f32x4 z = {0.f,0.f,0.f,0.f};
    f32x4 acc[8] = {z,z,z,z,z,z,z,z};
    #pragma unroll
    for(int nt=0; nt<8; nt++){
      const int k = kc*128 + nt*16 + lr;
      const ushort* bp = qk + ((size_t)k*B + bb)*1536 + (which ? 768 : 0) + h*64;
      short8 b0 = *(const short8*)(bp + lq*8);
      short8 b1 = *(const short8*)(bp + 32 + lq*8);
      acc[nt] = __builtin_amdgcn_mfma_f32_16x16x32_bf16(a0, b0, acc[nt], 0,0,0);
      acc[nt] = __builtin_amdgcn_mfma_f32_16x16x32_bf16(a1, b1, acc[nt], 0,0,0);
    }
    ushort* outp = which ? cqT : cpT;
    #pragma unroll
    for(int nt=0; nt<8; nt++){
      #pragma unroll
      for(int r=0;r<4;r++){
        int j = w*16 + lq*4 + r;
        int k = kc*128 + nt*16 + lr;
        outp[((size_t)bh*64 + j)*512 + k] = f2b(acc[nt][r]);
      }
    }
  } else {
    // K transpose: qk K-half [s][b][hh*64+d] -> kT[(bh*512 + s)*64 + d]
    const int id2 = id - 2304;                 // [0,96)
    const int bb = id2 / NH, hh = id2 - bb*NH;
    const int sl = t >> 3, d0 = (t & 7) * 8;
    const ushort* srcb = qk + (size_t)bb*1536 + H + hh*64 + d0;
    ushort* dstb = kT + ((size_t)id2*512 + sl)*64 + d0;
    #pragma unroll
    for(int i=0;i<16;i++){
      int s = i*32 + sl;
      *(short8*)(dstb + (size_t)i*32*64) = *(const short8*)(srcb + (size_t)s*B*1536);
    }
  }
}

// ---- fused attention, 32 q-rows per block; grid (bh=96, qt=16) ----
// K from dense kT, V from k-slab-major vt. cq gathers are hoisted into a
// dedicated LDS staging phase (cqs[q][k] = cqT[bh][pi(q,k)][k], 32KB, fully
// parallel, L2-resident source); the score loop is then MFMA+LDS+VALU only.
// Ps[32][520] later aliases the cqs slab (2 barriers apart).
__global__ __launch_bounds__(256)
void attn_kernel(const ushort* __restrict__ qk, const ushort* __restrict__ vt,
                 const ushort* __restrict__ kT,
                 const ushort* __restrict__ cpT, const ushort* __restrict__ cqT,
                 const unsigned char* __restrict__ bukg, ushort* __restrict__ ctx)
{
  const int bh = blockIdx.x, qt = blockIdx.y;
  const int b = bh / NH, hh = bh - b*NH;
  __shared__ ushort Qs[32][72];            //  4,608 B
  __shared__ float  cps[32][65];           //  8,320 B
  __shared__ ushort cqslab[32*520];        // 33,280 B; cq-gather early, Ps late
  __shared__ unsigned char bukl[1024];
  __shared__ float redm[4][32];
  __shared__ float reds[4][32];
  __shared__ float rowinv[32];
  const int t = threadIdx.x, w = t>>6, lane = t&63, lr = lane&15, lq = lane>>4;

  ((uint*)bukl)[t] = ((const uint*)bukg)[t & 255];
  for(int i=t; i<512; i+=256){
    int r = i >> 4, d0 = (i & 15) * 4;
    const ushort* src = qk + ((size_t)((qt*32 + r)*B + b))*1536 + hh*DH + d0;
    *(uint2*)&Qs[r][d0] = *(const uint2*)src;
  }
  for(int i=t; i<32*64; i+=256){
    int j = i >> 5, r = i & 31;
    cps[r][j] = b2f(cpT[((size_t)bh*64 + j)*512 + qt*32 + r]);
  }
  __syncthreads();   // bukl visible for the cq staging below

  // ---- cq staging: cqslab[q][k] = cqT[bh][pi(q,k)][k], 64 independent
  //      iterations/thread, adjacent lanes read adjacent k (coalesced runs) ----
  const ushort* cqbase = cqT + (size_t)bh*64*512;
  #pragma unroll 8
  for(int n=0; n<64; n++){
    int i = n*256 + t;
    int k = i & 511, q = i >> 9;
    int pi = (int)bukl[(qt*32 + q) - k + 511];
    cqslab[q*520 + k] = cqbase[(size_t)pi*512 + k];
  }
  __syncthreads();

  short8 a00 = *(const short8*)&Qs[lr][lq*8];
  short8 a01 = *(const short8*)&Qs[lr][32 + lq*8];
  short8 a10 = *(const short8*)&Qs[16 + lr][lq*8];
  short8 a11 = *(const short8*)&Qs[16 + lr][32 + lq*8];

  float sc[8][8];
  const int kbase = w * 128;
  const ushort* ktb = kT + (size_t)bh*512*64;
  f32x4 z4 = {0.f,0.f,0.f,0.f};
  #pragma unroll
  for(int tile=0; tile<8; tile++){
    const int k0 = kbase + tile*16;
    const ushort* kp = ktb + (size_t)(k0 + lr)*64 + lq*8;   // dense 2KB strip
    short8 b0 = *(const short8*)kp;
    short8 b1 = *(const short8*)(kp + 32);
    f32x4 acc[2] = {z4, z4};
    acc[0] = __builtin_amdgcn_mfma_f32_16x16x32_bf16(a00, b0, acc[0], 0,0,0);
    acc[0] = __builtin_amdgcn_mfma_f32_16x16x32_bf16(a01, b1, acc[0], 0,0,0);
    acc[1] = __builtin_amdgcn_mfma_f32_16x16x32_bf16(a10, b0, acc[1], 0,0,0);
    acc[1] = __builtin_amdgcn_mfma_f32_16x16x32_bf16(a11, b1, acc[1], 0,0,0);
    const int kcol = k0 + lr;
    #pragma unroll
    for(int qs=0;qs<2;qs++){
      #pragma unroll
      for(int r=0;r<4;r++){
        int ql = qs*16 + lq*4 + r;
        int pi = (int)bukl[(qt*32 + ql) - kcol + 511];
        sc[tile][qs*4+r] = (acc[qs][r] + cps[ql][pi]
                       + b2f(cqslab[ql*520 + kcol])) * SCALE;
      }
    }
  }

  float gm[8];
  #pragma unroll
  for(int j=0;j<8;j++){
    float m = sc[0][j];
    #pragma unroll
    for(int tile=1;tile<8;tile++) m = fmaxf(m, sc[tile][j]);
    #pragma unroll
    for(int off=1; off<16; off<<=1) m = fmaxf(m, __shfl_xor(m, off));
    if(lr==0) redm[w][(j>>2)*16 + lq*4 + (j&3)] = m;
  }
  __syncthreads();
  #pragma unroll
  for(int j=0;j<8;j++){
    int ql = (j>>2)*16 + lq*4 + (j&3);
    gm[j] = fmaxf(fmaxf(redm[0][ql],redm[1][ql]),fmaxf(redm[2][ql],redm[3][ql]));
  }
  #pragma unroll
  for(int j=0;j<8;j++){
    float s = 0.f;
    #pragma unroll
    for(int tile=0;tile<8;tile++){ float e = __expf(sc[tile][j]-gm[j]); sc[tile][j]=e; s+=e; }
    #pragma unroll
    for(int off=1; off<16; off<<=1) s += __shfl_xor(s, off);
    if(lr==0) reds[w][(j>>2)*16 + lq*4 + (j&3)] = s;
  }
  __syncthreads();            // last cqslab read was 2 barriers ago -> alias Ps
  #pragma unroll
  for(int j=0;j<8;j++){
    int ql = (j>>2)*16 + lq*4 + (j&3);
    float g = reds[0][ql]+reds[1][ql]+reds[2][ql]+reds[3][ql];
    if(w==0 && lr==0) rowinv[ql] = 1.0f/g;
  }
  ushort* Psp = cqslab;        // Ps[32][520] aliases the cq slab
  #pragma unroll
  for(int tile=0;tile<8;tile++){
    #pragma unroll
    for(int j=0;j<8;j++){
      int ql = (j>>2)*16 + lq*4 + (j&3);
      Psp[ql*520 + kbase + tile*16 + lr] = f2b(sc[tile][j]);
    }
  }
  __syncthreads();

  f32x4 acc2[2][3] = {{z4,z4,z4},{z4,z4,z4}};
  const ushort* vbh = vt + (size_t)bh*16*DV*32;
  #pragma unroll 4
  for(int kk=0; kk<S; kk+=32){
    short8 p0 = *(const short8*)&Psp[lr*520 + kk + lq*8];
    short8 p1 = *(const short8*)&Psp[(16 + lr)*520 + kk + lq*8];
    const ushort* vslab = vbh + (size_t)(kk>>5)*DV*32;
    #pragma unroll
    for(int ti=0; ti<3; ti++){
      const int v0 = (w*3 + ti)*16;
      short8 bv = *(const short8*)(vslab + (size_t)(v0 + lr)*32 + lq*8);  // dense 1KB strip
      acc2[0][ti] = __builtin_amdgcn_mfma_f32_16x16x32_bf16(p0, bv, acc2[0][ti], 0,0,0);
      acc2[1][ti] = __builtin_amdgcn_mfma_f32_16x16x32_bf16(p1, bv, acc2[1][ti], 0,0,0);
    }
  }
  #pragma unroll
  for(int qs=0;qs<2;qs++){
    #pragma unroll
    for(int ti=0; ti<3; ti++){
      const int v0 = (w*3 + ti)*16;
      #pragma unroll
      for(int r=0;r<4;r++){
        int ql = qs*16 + lq*4 + r;
        float val = acc2[qs][ti][r] * rowinv[ql];
        ctx[((size_t)((qt*32+ql)*B + b))*II + hh*DV + v0 + lr] = f2b(val);
      }
    }
  }
}

// ---- ctx2 = LN( (ctx + sigmoid(lskip)*gelu(value)) * gelu(gate) )  (bf16) ----
__global__ __launch_bounds__(256)
void glu_ln_kernel(const ushort* __restrict__ ctx, const ushort* __restrict__ vg,
                   const float* __restrict__ ls, ushort* __restrict__ outb)
{
  __shared__ float red[8];
  const int sb = blockIdx.x, t = threadIdx.x;
  const ushort* crow = ctx + (size_t)sb*II;
  const ushort* vrow = vg + (size_t)sb*2*II;
  float c[9]; float s=0.f, s2=0.f;
  #pragma unroll
  for(int i=0;i<9;i++){
    int idx = t + i*256;
    float cv  = b2f(crow[idx]);
    float val = b2f(vrow[idx]);
    float gt  = b2f(vrow[II + idx]);
    float sk  = 1.0f/(1.0f + __expf(-ls[idx]));
    cv = (cv + sk*gelu_f(val)) * gelu_f(gt);
    c[i]=cv; s+=cv; s2+=cv*cv;
  }
  block_sum2(s,s2,red,t);
  float mean = s*(1.0f/II);
  float rstd = rsqrtf(s2*(1.0f/II)-mean*mean+EPS);
  ushort* o = outb + (size_t)sb*II;
  #pragma unroll
  for(int i=0;i<9;i++) o[t+i*256] = f2b((c[i]-mean)*rstd);
}

// ---- final copy x(f32) -> out(f32) ----
__global__ __launch_bounds__(256)
void copy_kernel(const float* __restrict__ x, float* __restrict__ out){
  int i = (blockIdx.x*256 + threadIdx.x)*4;
  *(float4*)(out + i) = *(const float4*)(x + i);
}

extern "C" void kernel_launch(void* const* d_in, const int* in_sizes, int n_in,
                              void* d_out, int out_size, void* d_ws, size_t ws_size,
                              hipStream_t stream)
{
  (void)in_sizes; (void)n_in; (void)out_size; (void)ws_size;
  const int* ids      = (const int*)d_in[0];
  const int* pidx     = (const int*)d_in[2];
  const float* wemb   = (const float*)d_in[3];
  const float* rele   = (const float*)d_in[4];
  const float* rlw    = (const float*)d_in[5];
  const float* rlb    = (const float*)d_in[6];
  const float* Wv     = (const float*)d_in[7];
  const float* Wqk    = (const float*)d_in[8];
  const float* bqk    = (const float*)d_in[9];
  const float* Wo     = (const float*)d_in[10];
  const float* lskip  = (const float*)d_in[11];

  char* wsb = (char*)d_ws;
  float*  x     = (float*) (wsb + 0);           // 12,582,912 B
  ushort* h     = (ushort*)(wsb + 12582912);    //  6,291,456
  ushort* relb  = (ushort*)(wsb + 18874368);    //     98,304
  ushort* posb  = (ushort*)(wsb + 18972672);    //    196,608 (63 rows used of 64)
  ushort* vg    = (ushort*)(wsb + 19169280);    // 37,748,736
  ushort* qk    = (ushort*)(wsb + 56918016);    // 12,582,912
  ushort* cpT   = (ushort*)(wsb + 69500928);    //  6,291,456 (bf16 [96][64][512])
  ushort* cqT   = (ushort*)(wsb + 75792384);    //  6,291,456
  ushort* ctx   = (ushort*)(wsb + 82083840);    // 18,874,368
  ushort* vt    = (ushort*)(wsb + 100958208);   // 18,874,368 (k-slab-major layout)
  ushort* ctxln = vt;                           // alias: disjoint live ranges
  ushort* wvqk  = (ushort*)(wsb + 119832576);   // [Wv;Wqk;Wo] bf16 contiguous: 12,976,128
  ushort* wqkb  = wvqk + (size_t)NW0;
  ushort* wob   = wvqk + (size_t)(NW0 + NW1);   // ends ~132.8 MB
  // kT aliases h: h is dead after gemm_vgqk8 consumes it; vtcpq writes kT,
  // attn reads it, next layer's ln_x rewrites h afterward. Exact size match.
  ushort* kT    = h;                            // [96][512][64] bf16 = 6,291,456 B
  // bucket table lives in posb's unused 64th row (rows >= 63 never written)
  unsigned char* bukg = (unsigned char*)(posb + 63*1536);  // 1,024 B of 3,072 spare

  embed_ln_kernel<<<S*B, 256, 0, stream>>>(ids, wemb, x);
  rel_ln_kernel<<<63, 256, 0, stream>>>(rele, rlw, rlb, relb);
  bucket_kernel<<<4, 256, 0, stream>>>(pidx, bukg);

  for(int l=0; l<NL; l++){
    const float* Wv_l  = Wv  + (size_t)l * NW0;
    const float* Wqk_l = Wqk + (size_t)l * NW1;
    const float* bqk_l = bqk + (size_t)l * (2*H);
    const float* Wo_l  = Wo  + (size_t)l * NW2;
    const float* ls_l  = lskip + (size_t)l * II;

    f2b3_kernel<<<(NW0+NW1+NW2)/1024, 256, 0, stream>>>(Wv_l, Wqk_l, Wo_l, wvqk);
    ln_x_kernel<<<S*B, 256, 0, stream>>>(x, h);
    gemm_nt64<<<dim3((2*H)/64, 1), 256, 0, stream>>>(relb, wqkb, bqk_l, posb, 63, 2*H, H);
    gemm_vgqk8<<<768, 512, 0, stream>>>(h, wvqk, bqk_l, vg, qk);
    vtcpq_kernel<<<2400, 256, 0, stream>>>(vg, vt, qk, posb, cpT, cqT, kT);
    attn_kernel<<<dim3(B*NH, S/32), 256, 0, stream>>>(qk, vt, kT, cpT, cqT, bukg, ctx);
    glu_ln_kernel<<<S*B, 256, 0, stream>>>(ctx, vg, ls_l, ctxln);
    gemm128<2><<<dim3(H/128, (S*B)/128), 256, 0, stream>>>(ctxln, wob, nullptr, x, S*B, H, II);
  }
  copy_kernel<<<(S*B*H)/1024, 256, 0, stream>>>(x, (float*)d_out);
}

// Round 9
// 1236.187 us; speedup vs baseline: 1.0011x; 1.0011x over previous
//
#include <hip/hip_runtime.h>
#include <hip/hip_bf16.h>
#include <math.h>

#define S 512
#define B 8
#define H 768
#define NH 12
#define DH 64
#define DV 192
#define II 2304
#define NL 4
#define SCALE 0.07216878364870322f
#define EPS 1e-7f

#define NW0 (2*II*H)   // Wv elems  3,538,944
#define NW1 (2*H*H)    // Wqk elems 1,179,648
#define NW2 (H*II)     // Wo elems  1,769,472

typedef __attribute__((ext_vector_type(8))) short short8;
typedef __attribute__((ext_vector_type(4))) float f32x4;

__device__ __forceinline__ float b2f(ushort u){
  union { float f; unsigned int u; } v; v.u = ((unsigned int)u) << 16; return v.f;
}
__device__ __forceinline__ ushort f2b(float f){
  union { float f; unsigned int u; } v; v.f = f;
  unsigned int u = v.u;
  return (ushort)((u + 0x7fffu + ((u >> 16) & 1u)) >> 16);
}
__device__ __forceinline__ float gelu_f(float x){
  return 0.5f * x * (1.0f + erff(x * 0.70710678118654752f));
}
// async global(16B/lane) -> LDS (wave-uniform base + lane*16)
__device__ __forceinline__ void async_copy16(const ushort* g, ushort* l){
  __builtin_amdgcn_global_load_lds(
      (const __attribute__((address_space(1))) void*)g,
      (__attribute__((address_space(3))) void*)l, 16, 0, 0);
}

// ---- block-wide sum of two floats across 256 threads (4 waves) ----
__device__ __forceinline__ void block_sum2(float& s, float& s2, float* red, int t){
  #pragma unroll
  for(int off=32; off>=1; off>>=1){ s += __shfl_xor(s, off); s2 += __shfl_xor(s2, off); }
  int w = t >> 6;
  if((t & 63) == 0){ red[w] = s; red[4 + w] = s2; }
  __syncthreads();
  s  = red[0] + red[1] + red[2] + red[3];
  s2 = red[4] + red[5] + red[6] + red[7];
}

// ---- fused f32->bf16 convert of Wv|Wqk|Wo into one contiguous bf16 buffer ----
__global__ __launch_bounds__(256)
void f2b3_kernel(const float* __restrict__ in0, const float* __restrict__ in1,
                 const float* __restrict__ in2, ushort* __restrict__ out){
  int i = (blockIdx.x * 256 + threadIdx.x) * 4;
  const float* src; int off;
  if(i < NW0){ src = in0; off = i; }
  else if(i < NW0+NW1){ src = in1; off = i - NW0; }
  else { src = in2; off = i - NW0 - NW1; }
  float4 v = *(const float4*)(src + off);
  __attribute__((aligned(8))) ushort tmp[4] = { f2b(v.x), f2b(v.y), f2b(v.z), f2b(v.w) };
  *(uint2*)(out + i) = *(const uint2*)tmp;
}

// ---- x = LN(word_emb[ids])  (f32 in, f32 out) ----
__global__ __launch_bounds__(256)
void embed_ln_kernel(const int* __restrict__ ids, const float* __restrict__ wemb,
                     float* __restrict__ x)
{
  __shared__ float red[8];
  const int sb = blockIdx.x, t = threadIdx.x;
  const float* row = wemb + (size_t)ids[sb] * H;
  float v0 = row[t], v1 = row[t+256], v2 = row[t+512];
  float s = v0+v1+v2, s2 = v0*v0+v1*v1+v2*v2;
  block_sum2(s, s2, red, t);
  float mean = s * (1.0f/H);
  float rstd = rsqrtf(s2*(1.0f/H) - mean*mean + EPS);
  float* xo = x + (size_t)sb * H;
  xo[t]     = (v0-mean)*rstd;
  xo[t+256] = (v1-mean)*rstd;
  xo[t+512] = (v2-mean)*rstd;
}

// ---- relb = LN(rel_emb)*w + b  (f32 in, bf16 out) ----
__global__ __launch_bounds__(256)
void rel_ln_kernel(const float* __restrict__ rel_emb, const float* __restrict__ w,
                   const float* __restrict__ bia, ushort* __restrict__ outb)
{
  __shared__ float red[8];
  const int j = blockIdx.x, t = threadIdx.x;
  const float* row = rel_emb + (size_t)j * H;
  float v0=row[t], v1=row[t+256], v2=row[t+512];
  float s=v0+v1+v2, s2=v0*v0+v1*v1+v2*v2;
  block_sum2(s,s2,red,t);
  float mean = s*(1.0f/H);
  float rstd = rsqrtf(s2*(1.0f/H)-mean*mean+EPS);
  ushort* o = outb + (size_t)j*H;
  o[t]     = f2b((v0-mean)*rstd * w[t]     + bia[t]);
  o[t+256] = f2b((v1-mean)*rstd * w[t+256] + bia[t+256]);
  o[t+512] = f2b((v2-mean)*rstd * w[t+512] + bia[t+512]);
}

// ---- h = LN(x)  (bf16 out) ----
__global__ __launch_bounds__(256)
void ln_x_kernel(const float* __restrict__ x, ushort* __restrict__ h)
{
  __shared__ float red[8];
  const int sb = blockIdx.x, t = threadIdx.x;
  const float* row = x + (size_t)sb * H;
  float v0 = row[t], v1 = row[t+256], v2 = row[t+512];
  float s = v0+v1+v2, s2 = v0*v0+v1*v1+v2*v2;
  block_sum2(s, s2, red, t);
  float mean = s * (1.0f/H);
  float rstd = rsqrtf(s2*(1.0f/H) - mean*mean + EPS);
  ushort* o = h + (size_t)sb * H;
  o[t]     = f2b((v0-mean)*rstd);
  o[t+256] = f2b((v1-mean)*rstd);
  o[t+512] = f2b((v2-mean)*rstd);
}

// ---- bucket table: pidx depends only on (q-k); sample row 0 / row 511 ----
__global__ __launch_bounds__(256)
void bucket_kernel(const int* __restrict__ pidx, unsigned char* __restrict__ buk){
  int r = blockIdx.x*256 + threadIdx.x;   // [0,1024)
  int rel = r - 511;
  int v = 0;
  if(rel <= 0)          v = pidx[-rel];               // row 0, col -rel
  else if(rel <= 511)   v = pidx[511*S + (511-rel)];  // row 511
  buk[r] = (unsigned char)v;
}

// ---- small GEMM (64x64 tile): pos = relb @ Wqk^T + bqk (M=63) ----
__global__ __launch_bounds__(256)
void gemm_nt64(const ushort* __restrict__ A, const ushort* __restrict__ Bw,
               const float* __restrict__ bias, ushort* __restrict__ Cout,
               int M, int N, int K)
{
  __shared__ ushort As[64][40];
  __shared__ ushort Bs[64][40];
  const int n0 = blockIdx.x * 64, m0 = blockIdx.y * 64;
  const int t = threadIdx.x;
  const int lrow = t >> 2, lk = (t & 3) * 8;
  const int lane = t & 63, w = t >> 6, lr = lane & 15, lq = lane >> 4;
  const int wr = (w >> 1) * 32, wc = (w & 1) * 32;
  f32x4 z = {0.f,0.f,0.f,0.f};
  f32x4 acc[2][2] = {{z,z},{z,z}};
  const int arow = m0 + lrow;
  const ushort* aptr = A  + (size_t)arow * K + lk;
  const ushort* bptr = Bw + (size_t)(n0 + lrow) * K + lk;
  for(int k0 = 0; k0 < K; k0 += 32){
    short8 av = {0,0,0,0,0,0,0,0};
    if(arow < M) av = *(const short8*)(aptr + k0);
    short8 bv = *(const short8*)(bptr + k0);
    __syncthreads();
    *(short8*)&As[lrow][lk] = av;
    *(short8*)&Bs[lrow][lk] = bv;
    __syncthreads();
    short8 a0 = *(const short8*)&As[wr + lr][lq * 8];
    short8 a1 = *(const short8*)&As[wr + 16 + lr][lq * 8];
    short8 b0 = *(const short8*)&Bs[wc + lr][lq * 8];
    short8 b1 = *(const short8*)&Bs[wc + 16 + lr][lq * 8];
    acc[0][0] = __builtin_amdgcn_mfma_f32_16x16x32_bf16(a0, b0, acc[0][0], 0,0,0);
    acc[0][1] = __builtin_amdgcn_mfma_f32_16x16x32_bf16(a0, b1, acc[0][1], 0,0,0);
    acc[1][0] = __builtin_amdgcn_mfma_f32_16x16x32_bf16(a1, b0, acc[1][0], 0,0,0);
    acc[1][1] = __builtin_amdgcn_mfma_f32_16x16x32_bf16(a1, b1, acc[1][1], 0,0,0);
  }
  #pragma unroll
  for(int i=0;i<2;i++){
    #pragma unroll
    for(int j=0;j<2;j++){
      #pragma unroll
      for(int r=0;r<4;r++){
        int m = m0 + wr + i*16 + lq*4 + r;
        int n = n0 + wc + j*16 + lr;
        if(m >= M) continue;
        float v = acc[i][j][r];
        if(bias) v += bias[n];
        Cout[(size_t)m*N + n] = f2b(v);
      }
    }
  }
}

// ---- main GEMM: 128x128 tile, BK=64 (two 32-col LDS slabs) ----
// OUT_MODE: 0 = f32 store, 1 = bf16 store, 2 = f32 accumulate (+=)
template<int OUT_MODE>
__global__ __launch_bounds__(256)
void gemm128(const ushort* __restrict__ A, const ushort* __restrict__ Bw,
             const float* __restrict__ bias, void* __restrict__ Cout,
             int M, int N, int K)
{
  __shared__ ushort As[2][128*32];
  __shared__ ushort Bs[2][128*32];
  const int t = threadIdx.x, w = t>>6, lane = t&63, lr = lane&15, lq = lane>>4;
  const int m0 = blockIdx.y*128, n0 = blockIdx.x*128;
  const int wr = (w>>1)*64, wc = (w&1)*64;
  const int srow = (w*2)*16 + (lane>>2);
  const int sk = (lane&3)*8;
  const ushort* aG = A  + (size_t)(m0+srow)*K + sk;
  const ushort* bG = Bw + (size_t)(n0+srow)*K + sk;
  f32x4 z = {0.f,0.f,0.f,0.f};
  f32x4 acc[4][4] = {{z,z,z,z},{z,z,z,z},{z,z,z,z},{z,z,z,z}};
  for(int k0 = 0; k0 < K; k0 += 64){
    __syncthreads();
    #pragma unroll
    for(int s=0;s<2;s++){
      async_copy16(aG + k0 + s*32,                 As[s] + (w*2)*512);
      async_copy16(aG + k0 + s*32 + (size_t)16*K,  As[s] + (w*2+1)*512);
      async_copy16(bG + k0 + s*32,                 Bs[s] + (w*2)*512);
      async_copy16(bG + k0 + s*32 + (size_t)16*K,  Bs[s] + (w*2+1)*512);
    }
    __syncthreads();
    #pragma unroll
    for(int s=0;s<2;s++){
      short8 af[4], bf[4];
      #pragma unroll
      for(int i=0;i<4;i++) af[i] = *(const short8*)&As[s][(wr + i*16 + lr)*32 + lq*8];
      #pragma unroll
      for(int j=0;j<4;j++) bf[j] = *(const short8*)&Bs[s][(wc + j*16 + lr)*32 + lq*8];
      #pragma unroll
      for(int i=0;i<4;i++)
        #pragma unroll
        for(int j=0;j<4;j++)
          acc[i][j] = __builtin_amdgcn_mfma_f32_16x16x32_bf16(af[i], bf[j], acc[i][j], 0,0,0);
    }
  }
  #pragma unroll
  for(int i=0;i<4;i++){
    #pragma unroll
    for(int j=0;j<4;j++){
      #pragma unroll
      for(int r=0;r<4;r++){
        int m = m0 + wr + i*16 + lq*4 + r;
        int n = n0 + wc + j*16 + lr;
        float v = acc[i][j][r];
        if(bias) v += bias[n];
        if(OUT_MODE == 0)      ((float*) Cout)[(size_t)m*N + n] = v;
        else if(OUT_MODE == 1) ((ushort*)Cout)[(size_t)m*N + n] = f2b(v);
        else                   ((float*) Cout)[(size_t)m*N + n] += v;
      }
    }
  }
}

// ---- vg+qk GEMM v9: 128x128 tile, 256 threads (4 waves 2x2), double-buffered
// depth-1 prefetch. Per K-tile exactly ONE __syncthreads (its vmcnt(0) waits
// only on the prefetch issued a full tile earlier -> cheap), then stage(kt+1)
// into the other named buffer, then UNFENCED ds_read+MFMA so the compiler's
// counted lgkmcnt interleaves them (r8 lesson: mid-tile barriers/sched_barrier
// fences serialized read<->MFMA; VALU+MFMA summed to 33%). 64KB LDS -> 2
// blocks/CU for cross-block latency hiding. XOR swizzle kept (0 conflicts). ----
#define VGQK9_STAGE(KT, SA, SB) do {                                           \
    const int k0_ = (KT)*64;                                                   \
    async_copy16(aSrc + k0_,                 (SA) + dA);                       \
    async_copy16(aSrc + (size_t)32*K + k0_,  (SA) + 2048  + dA);               \
    async_copy16(aSrc + (size_t)64*K + k0_,  (SA) + 4096  + dA);               \
    async_copy16(aSrc + (size_t)96*K + k0_,  (SA) + 6144  + dA);               \
    async_copy16(bSrc + k0_,                 (SB) + dA);                       \
    async_copy16(bSrc + (size_t)32*K + k0_,  (SB) + 2048  + dA);               \
    async_copy16(bSrc + (size_t)64*K + k0_,  (SB) + 4096  + dA);               \
    async_copy16(bSrc + (size_t)96*K + k0_,  (SB) + 6144  + dA);               \
  } while(0)

#define VGQK9_TILE(KT, CA, CB, SA, SB) do {                                    \
    __syncthreads();                                                           \
    if((KT)+1 < NT) VGQK9_STAGE((KT)+1, SA, SB);                               \
    short8 af_[4][2], bf_[4][2];                                               \
    _Pragma("unroll")                                                          \
    for(int i=0;i<4;i++)                                                       \
      _Pragma("unroll")                                                        \
      for(int ks=0;ks<2;ks++)                                                  \
        af_[i][ks] = *(const short8*)&(CA)[(wr + i*16 + lr)*64 + ((ks*32 + lq*8) ^ rxor)]; \
    _Pragma("unroll")                                                          \
    for(int j=0;j<4;j++)                                                       \
      _Pragma("unroll")                                                        \
      for(int ks=0;ks<2;ks++)                                                  \
        bf_[j][ks] = *(const short8*)&(CB)[(wc + j*16 + lr)*64 + ((ks*32 + lq*8) ^ rxor)]; \
    _Pragma("unroll")                                                          \
    for(int i=0;i<4;i++)                                                       \
      _Pragma("unroll")                                                        \
      for(int j=0;j<4;j++)                                                     \
        _Pragma("unroll")                                                      \
        for(int ks=0;ks<2;ks++)                                                \
          acc[i][j] = __builtin_amdgcn_mfma_f32_16x16x32_bf16(af_[i][ks], bf_[j][ks], acc[i][j], 0,0,0); \
  } while(0)

__global__ __launch_bounds__(256)
void gemm_vgqk9(const ushort* __restrict__ A, const ushort* __restrict__ Ww,
                const float* __restrict__ bqk, ushort* __restrict__ vg,
                ushort* __restrict__ qk)
{
  constexpr int K  = H;        // 768
  constexpr int NT = K / 64;   // 12 k-tiles (even)
  // per buffer: [128 rows][64 cols] bf16 = 16KB; 4 buffers = 64KB -> 2 blk/CU
  __shared__ ushort As0[8192];
  __shared__ ushort Bs0[8192];
  __shared__ ushort As1[8192];
  __shared__ ushort Bs1[8192];
  const int t = threadIdx.x;
  const int w = t >> 6, l = t & 63, lr = l & 15, lq = l >> 4;
  const int wr = (w >> 1) * 64, wc = (w & 1) * 64;
  // bijective XCD swizzle: 1536 blocks = 8 XCDs x 192; chunk = 6 B-panels x 32 m
  int id = blockIdx.x;
  int swz = (id & 7) * 192 + (id >> 3);
  const int bm = swz & 31, bn = swz >> 5;     // 32 m-blocks, 48 n-blocks
  const int m0 = bm * 128, n0 = bn * 128;

  // staging: each gload_lds = 4KB (256 thr x 16B) = 32 rows; thread t covers
  // row (t>>3), 16B-chunk (t&7). LDS dest linear; SOURCE col pre-swizzled with
  // the involution the reads use: chunk' = chunk ^ (row&7).
  const int srow = t >> 3;
  const int scol = ((t & 7) ^ (srow & 7)) << 3;  // ushort units
  const ushort* aSrc = A  + (size_t)(m0 + srow) * K + scol;
  const ushort* bSrc = Ww + (size_t)(n0 + srow) * K + scol;
  const int dA = w * 512;                     // wave's 1KB slot within a 32-row step
  const int rxor = (lr & 7) << 3;             // read-side swizzle (ushort units)

  f32x4 z = {0.f,0.f,0.f,0.f};
  f32x4 acc[4][4] = {{z,z,z,z},{z,z,z,z},{z,z,z,z},{z,z,z,z}};

  VGQK9_STAGE(0, As0, Bs0);                   // prologue: tile 0 -> buf0

  for(int m2 = 0; m2 < NT/2; m2++){
    const int kt = 2*m2;
    VGQK9_TILE(kt,   As0, Bs0, As1, Bs1);
    VGQK9_TILE(kt+1, As1, Bs1, As0, Bs0);
  }

  const bool is_qk = (n0 >= 2*II);
  #pragma unroll
  for(int i=0;i<4;i++){
    #pragma unroll
    for(int j=0;j<4;j++){
      #pragma unroll
      for(int r=0;r<4;r++){
        int m = m0 + wr + i*16 + lq*4 + r;
        int n = n0 + wc + j*16 + lr;
        float v = acc[i][j][r];
        if(is_qk){
          int nq = n - 2*II;
          qk[(size_t)m*(2*H) + nq] = f2b(v + bqk[nq]);
        } else {
          vg[(size_t)m*(2*II) + n] = f2b(v);
        }
      }
    }
  }
}

// ---- merged: Vt transpose (blocks [0,1536)) + cp/cq MFMA ([1536,2304))
//      + K transpose ([2304,2400)): kT[bh][s][64] for coalesced attn K reads ----
__global__ __launch_bounds__(256)
void vtcpq_kernel(const ushort* __restrict__ vg, ushort* __restrict__ vt,
                  const ushort* __restrict__ qk, const ushort* __restrict__ posb,
                  ushort* __restrict__ cpT, ushort* __restrict__ cqT,
                  ushort* __restrict__ kT)
{
  const int id = blockIdx.x;
  const int t = threadIdx.x;
  __shared__ ushort tile[32][200];
  if(id < 1536){
    const int st = id & 15;
    const int hh = (id >> 4) % 12;
    const int b  = id / 192;
    {
      int sl = t >> 3, v0 = (t & 7) * 24;
      const ushort* src = vg + ((size_t)((st*32 + sl)*B + b))*(2*II) + hh*DV + v0;
      *(short8*)&tile[sl][v0]      = *(const short8*)(src);
      *(short8*)&tile[sl][v0 + 8]  = *(const short8*)(src + 8);
      *(short8*)&tile[sl][v0 + 16] = *(const short8*)(src + 16);
    }
    __syncthreads();
    if(t < DV){
      __attribute__((aligned(16))) ushort tmp[32];
      #pragma unroll
      for(int s2=0;s2<32;s2++) tmp[s2] = tile[s2][t];
      // k-slab-major layout: vt[((bh*16 + st)*DV + v)*32 + c]  (fully coalesced)
      ushort* dst = vt + ((((size_t)(b*NH + hh))*16 + st)*DV + t)*32;
      #pragma unroll
      for(int c=0;c<32;c+=8) *(short8*)(dst + c) = *(const short8*)&tmp[c];
    }
  } else if(id < 2304){
    const int jid = id - 1536;
    const int kc = jid & 3;
    const int bh = (jid >> 2) % 96;
    const int which = jid / 384;
    const int bb = bh / NH, h = bh - bb*NH;
    const int w = t>>6, lane = t&63, lr = lane&15, lq = lane>>4;
    const ushort* ab = posb + (size_t)(w*16 + lr)*1536 + (which ? 0 : 768) + h*64;
    short8 a0 = *(const short8*)(ab + lq*8);
    short8 a1 = *(const short8*)(ab + 32 + lq*8);
    f32x4 z = {0.f,0.f,0.f,0.f};
    f32x4 acc[8] = {z,z,z,z,z,z,z,z};
    #pragma unroll
    for(int nt=0; nt<8; nt++){
      const int k = kc*128 + nt*16 + lr;
      const ushort* bp = qk + ((size_t)k*B + bb)*1536 + (which ? 768 : 0) + h*64;
      short8 b0 = *(const short8*)(bp + lq*8);
      short8 b1 = *(const short8*)(bp + 32 + lq*8);
      acc[nt] = __builtin_amdgcn_mfma_f32_16x16x32_bf16(a0, b0, acc[nt], 0,0,0);
      acc[nt] = __builtin_amdgcn_mfma_f32_16x16x32_bf16(a1, b1, acc[nt], 0,0,0);
    }
    ushort* outp = which ? cqT : cpT;
    #pragma unroll
    for(int nt=0; nt<8; nt++){
      #pragma unroll
      for(int r=0;r<4;r++){
        int j = w*16 + lq*4 + r;
        int k = kc*128 + nt*16 + lr;
        outp[((size_t)bh*64 + j)*512 + k] = f2b(acc[nt][r]);
      }
    }
  } else {
    // K transpose: qk K-half [s][b][hh*64+d] -> kT[(bh*512 + s)*64 + d]
    const int id2 = id - 2304;                 // [0,96)
    const int bb = id2 / NH, hh = id2 - bb*NH;
    const int sl = t >> 3, d0 = (t & 7) * 8;
    const ushort* srcb = qk + (size_t)bb*1536 + H + hh*64 + d0;
    ushort* dstb = kT + ((size_t)id2*512 + sl)*64 + d0;
    #pragma unroll
    for(int i=0;i<16;i++){
      int s = i*32 + sl;
      *(short8*)(dstb + (size_t)i*32*64) = *(const short8*)(srcb + (size_t)s*B*1536);
    }
  }
}

// ---- fused attention, 32 q-rows per block; grid (bh=96, qt=16) ----
// K from dense kT, V from k-slab-major vt. cq gathers are hoisted into a
// dedicated LDS staging phase (cqs[q][k] = cqT[bh][pi(q,k)][k], 32KB, fully
// parallel, L2-resident source); the score loop is then MFMA+LDS+VALU only.
// Ps[32][520] later aliases the cqs slab (2 barriers apart).
__global__ __launch_bounds__(256)
void attn_kernel(const ushort* __restrict__ qk, const ushort* __restrict__ vt,
                 const ushort* __restrict__ kT,
                 const ushort* __restrict__ cpT, const ushort* __restrict__ cqT,
                 const unsigned char* __restrict__ bukg, ushort* __restrict__ ctx)
{
  const int bh = blockIdx.x, qt = blockIdx.y;
  const int b = bh / NH, hh = bh - b*NH;
  __shared__ ushort Qs[32][72];            //  4,608 B
  __shared__ float  cps[32][65];           //  8,320 B
  __shared__ ushort cqslab[32*520];        // 33,280 B; cq-gather early, Ps late
  __shared__ unsigned char bukl[1024];
  __shared__ float redm[4][32];
  __shared__ float reds[4][32];
  __shared__ float rowinv[32];
  const int t = threadIdx.x, w = t>>6, lane = t&63, lr = lane&15, lq = lane>>4;

  ((uint*)bukl)[t] = ((const uint*)bukg)[t & 255];
  for(int i=t; i<512; i+=256){
    int r = i >> 4, d0 = (i & 15) * 4;
    const ushort* src = qk + ((size_t)((qt*32 + r)*B + b))*1536 + hh*DH + d0;
    *(uint2*)&Qs[r][d0] = *(const uint2*)src;
  }
  for(int i=t; i<32*64; i+=256){
    int j = i >> 5, r = i & 31;
    cps[r][j] = b2f(cpT[((size_t)bh*64 + j)*512 + qt*32 + r]);
  }
  __syncthreads();   // bukl visible for the cq staging below

  // ---- cq staging: cqslab[q][k] = cqT[bh][pi(q,k)][k], 64 independent
  //      iterations/thread, adjacent lanes read adjacent k (coalesced runs) ----
  const ushort* cqbase = cqT + (size_t)bh*64*512;
  #pragma unroll 8
  for(int n=0; n<64; n++){
    int i = n*256 + t;
    int k = i & 511, q = i >> 9;
    int pi = (int)bukl[(qt*32 + q) - k + 511];
    cqslab[q*520 + k] = cqbase[(size_t)pi*512 + k];
  }
  __syncthreads();

  short8 a00 = *(const short8*)&Qs[lr][lq*8];
  short8 a01 = *(const short8*)&Qs[lr][32 + lq*8];
  short8 a10 = *(const short8*)&Qs[16 + lr][lq*8];
  short8 a11 = *(const short8*)&Qs[16 + lr][32 + lq*8];

  float sc[8][8];
  const int kbase = w * 128;
  const ushort* ktb = kT + (size_t)bh*512*64;
  f32x4 z4 = {0.f,0.f,0.f,0.f};
  #pragma unroll
  for(int tile=0; tile<8; tile++){
    const int k0 = kbase + tile*16;
    const ushort* kp = ktb + (size_t)(k0 + lr)*64 + lq*8;   // dense 2KB strip
    short8 b0 = *(const short8*)kp;
    short8 b1 = *(const short8*)(kp + 32);
    f32x4 acc[2] = {z4, z4};
    acc[0] = __builtin_amdgcn_mfma_f32_16x16x32_bf16(a00, b0, acc[0], 0,0,0);
    acc[0] = __builtin_amdgcn_mfma_f32_16x16x32_bf16(a01, b1, acc[0], 0,0,0);
    acc[1] = __builtin_amdgcn_mfma_f32_16x16x32_bf16(a10, b0, acc[1], 0,0,0);
    acc[1] = __builtin_amdgcn_mfma_f32_16x16x32_bf16(a11, b1, acc[1], 0,0,0);
    const int kcol = k0 + lr;
    #pragma unroll
    for(int qs=0;qs<2;qs++){
      #pragma unroll
      for(int r=0;r<4;r++){
        int ql = qs*16 + lq*4 + r;
        int pi = (int)bukl[(qt*32 + ql) - kcol + 511];
        sc[tile][qs*4+r] = (acc[qs][r] + cps[ql][pi]
                       + b2f(cqslab[ql*520 + kcol])) * SCALE;
      }
    }
  }

  float gm[8];
  #pragma unroll
  for(int j=0;j<8;j++){
    float m = sc[0][j];
    #pragma unroll
    for(int tile=1;tile<8;tile++) m = fmaxf(m, sc[tile][j]);
    #pragma unroll
    for(int off=1; off<16; off<<=1) m = fmaxf(m, __shfl_xor(m, off));
    if(lr==0) redm[w][(j>>2)*16 + lq*4 + (j&3)] = m;
  }
  __syncthreads();
  #pragma unroll
  for(int j=0;j<8;j++){
    int ql = (j>>2)*16 + lq*4 + (j&3);
    gm[j] = fmaxf(fmaxf(redm[0][ql],redm[1][ql]),fmaxf(redm[2][ql],redm[3][ql]));
  }
  #pragma unroll
  for(int j=0;j<8;j++){
    float s = 0.f;
    #pragma unroll
    for(int tile=0;tile<8;tile++){ float e = __expf(sc[tile][j]-gm[j]); sc[tile][j]=e; s+=e; }
    #pragma unroll
    for(int off=1; off<16; off<<=1) s += __shfl_xor(s, off);
    if(lr==0) reds[w][(j>>2)*16 + lq*4 + (j&3)] = s;
  }
  __syncthreads();            // last cqslab read was 2 barriers ago -> alias Ps
  #pragma unroll
  for(int j=0;j<8;j++){
    int ql = (j>>2)*16 + lq*4 + (j&3);
    float g = reds[0][ql]+reds[1][ql]+reds[2][ql]+reds[3][ql];
    if(w==0 && lr==0) rowinv[ql] = 1.0f/g;
  }
  ushort* Psp = cqslab;        // Ps[32][520] aliases the cq slab
  #pragma unroll
  for(int tile=0;tile<8;tile++){
    #pragma unroll
    for(int j=0;j<8;j++){
      int ql = (j>>2)*16 + lq*4 + (j&3);
      Psp[ql*520 + kbase + tile*16 + lr] = f2b(sc[tile][j]);
    }
  }
  __syncthreads();

  f32x4 acc2[2][3] = {{z4,z4,z4},{z4,z4,z4}};
  const ushort* vbh = vt + (size_t)bh*16*DV*32;
  #pragma unroll 4
  for(int kk=0; kk<S; kk+=32){
    short8 p0 = *(const short8*)&Psp[lr*520 + kk + lq*8];
    short8 p1 = *(const short8*)&Psp[(16 + lr)*520 + kk + lq*8];
    const ushort* vslab = vbh + (size_t)(kk>>5)*DV*32;
    #pragma unroll
    for(int ti=0; ti<3; ti++){
      const int v0 = (w*3 + ti)*16;
      short8 bv = *(const short8*)(vslab + (size_t)(v0 + lr)*32 + lq*8);  // dense 1KB strip
      acc2[0][ti] = __builtin_amdgcn_mfma_f32_16x16x32_bf16(p0, bv, acc2[0][ti], 0,0,0);
      acc2[1][ti] = __builtin_amdgcn_mfma_f32_16x16x32_bf16(p1, bv, acc2[1][ti], 0,0,0);
    }
  }
  #pragma unroll
  for(int qs=0;qs<2;qs++){
    #pragma unroll
    for(int ti=0; ti<3; ti++){
      const int v0 = (w*3 + ti)*16;
      #pragma unroll
      for(int r=0;r<4;r++){
        int ql = qs*16 + lq*4 + r;
        float val = acc2[qs][ti][r] * rowinv[ql];
        ctx[((size_t)((qt*32+ql)*B + b))*II + hh*DV + v0 + lr] = f2b(val);
      }
    }
  }
}

// ---- ctx2 = LN( (ctx + sigmoid(lskip)*gelu(value)) * gelu(gate) )  (bf16) ----
__global__ __launch_bounds__(256)
void glu_ln_kernel(const ushort* __restrict__ ctx, const ushort* __restrict__ vg,
                   const float* __restrict__ ls, ushort* __restrict__ outb)
{
  __shared__ float red[8];
  const int sb = blockIdx.x, t = threadIdx.x;
  const ushort* crow = ctx + (size_t)sb*II;
  const ushort* vrow = vg + (size_t)sb*2*II;
  float c[9]; float s=0.f, s2=0.f;
  #pragma unroll
  for(int i=0;i<9;i++){
    int idx = t + i*256;
    float cv  = b2f(crow[idx]);
    float val = b2f(vrow[idx]);
    float gt  = b2f(vrow[II + idx]);
    float sk  = 1.0f/(1.0f + __expf(-ls[idx]));
    cv = (cv + sk*gelu_f(val)) * gelu_f(gt);
    c[i]=cv; s+=cv; s2+=cv*cv;
  }
  block_sum2(s,s2,red,t);
  float mean = s*(1.0f/II);
  float rstd = rsqrtf(s2*(1.0f/II)-mean*mean+EPS);
  ushort* o = outb + (size_t)sb*II;
  #pragma unroll
  for(int i=0;i<9;i++) o[t+i*256] = f2b((c[i]-mean)*rstd);
}

// ---- final copy x(f32) -> out(f32) ----
__global__ __launch_bounds__(256)
void copy_kernel(const float* __restrict__ x, float* __restrict__ out){
  int i = (blockIdx.x*256 + threadIdx.x)*4;
  *(float4*)(out + i) = *(const float4*)(x + i);
}

extern "C" void kernel_launch(void* const* d_in, const int* in_sizes, int n_in,
                              void* d_out, int out_size, void* d_ws, size_t ws_size,
                              hipStream_t stream)
{
  (void)in_sizes; (void)n_in; (void)out_size; (void)ws_size;
  const int* ids      = (const int*)d_in[0];
  const int* pidx     = (const int*)d_in[2];
  const float* wemb   = (const float*)d_in[3];
  const float* rele   = (const float*)d_in[4];
  const float* rlw    = (const float*)d_in[5];
  const float* rlb    = (const float*)d_in[6];
  const float* Wv     = (const float*)d_in[7];
  const float* Wqk    = (const float*)d_in[8];
  const float* bqk    = (const float*)d_in[9];
  const float* Wo     = (const float*)d_in[10];
  const float* lskip  = (const float*)d_in[11];

  char* wsb = (char*)d_ws;
  float*  x     = (float*) (wsb + 0);           // 12,582,912 B
  ushort* h     = (ushort*)(wsb + 12582912);    //  6,291,456
  ushort* relb  = (ushort*)(wsb + 18874368);    //     98,304
  ushort* posb  = (ushort*)(wsb + 18972672);    //    196,608 (63 rows used of 64)
  ushort* vg    = (ushort*)(wsb + 19169280);    // 37,748,736
  ushort* qk    = (ushort*)(wsb + 56918016);    // 12,582,912
  ushort* cpT   = (ushort*)(wsb + 69500928);    //  6,291,456 (bf16 [96][64][512])
  ushort* cqT   = (ushort*)(wsb + 75792384);    //  6,291,456
  ushort* ctx   = (ushort*)(wsb + 82083840);    // 18,874,368
  ushort* vt    = (ushort*)(wsb + 100958208);   // 18,874,368 (k-slab-major layout)
  ushort* ctxln = vt;                           // alias: disjoint live ranges
  ushort* wvqk  = (ushort*)(wsb + 119832576);   // [Wv;Wqk;Wo] bf16 contiguous: 12,976,128
  ushort* wqkb  = wvqk + (size_t)NW0;
  ushort* wob   = wvqk + (size_t)(NW0 + NW1);   // ends ~132.8 MB
  // kT aliases h: h is dead after gemm_vgqk9 consumes it; vtcpq writes kT,
  // attn reads it, next layer's ln_x rewrites h afterward. Exact size match.
  ushort* kT    = h;                            // [96][512][64] bf16 = 6,291,456 B
  // bucket table lives in posb's unused 64th row (rows >= 63 never written)
  unsigned char* bukg = (unsigned char*)(posb + 63*1536);  // 1,024 B of 3,072 spare

  embed_ln_kernel<<<S*B, 256, 0, stream>>>(ids, wemb, x);
  rel_ln_kernel<<<63, 256, 0, stream>>>(rele, rlw, rlb, relb);
  bucket_kernel<<<4, 256, 0, stream>>>(pidx, bukg);

  for(int l=0; l<NL; l++){
    const float* Wv_l  = Wv  + (size_t)l * NW0;
    const float* Wqk_l = Wqk + (size_t)l * NW1;
    const float* bqk_l = bqk + (size_t)l * (2*H);
    const float* Wo_l  = Wo  + (size_t)l * NW2;
    const float* ls_l  = lskip + (size_t)l * II;

    f2b3_kernel<<<(NW0+NW1+NW2)/1024, 256, 0, stream>>>(Wv_l, Wqk_l, Wo_l, wvqk);
    ln_x_kernel<<<S*B, 256, 0, stream>>>(x, h);
    gemm_nt64<<<dim3((2*H)/64, 1), 256, 0, stream>>>(relb, wqkb, bqk_l, posb, 63, 2*H, H);
    gemm_vgqk9<<<1536, 256, 0, stream>>>(h, wvqk, bqk_l, vg, qk);
    vtcpq_kernel<<<2400, 256, 0, stream>>>(vg, vt, qk, posb, cpT, cqT, kT);
    attn_kernel<<<dim3(B*NH, S/32), 256, 0, stream>>>(qk, vt, kT, cpT, cqT, bukg, ctx);
    glu_ln_kernel<<<S*B, 256, 0, stream>>>(ctx, vg, ls_l, ctxln);
    gemm128<2><<<dim3(H/128, (S*B)/128), 256, 0, stream>>>(ctxln, wob, nullptr, x, S*B, H, II);
  }
  copy_kernel<<<(S*B*H)/1024, 256, 0, stream>>>(x, (float*)d_out);
}

// Round 10
// 1193.829 us; speedup vs baseline: 1.0366x; 1.0355x over previous
//
#include <hip/hip_runtime.h>
#include <hip/hip_bf16.h>
#include <math.h>

#define S 512
#define B 8
#define H 768
#define NH 12
#define DH 64
#define DV 192
#define II 2304
#define NL 4
#define SCALE 0.07216878364870322f
#define EPS 1e-7f

#define NW0 (2*II*H)   // Wv elems  3,538,944
#define NW1 (2*H*H)    // Wqk elems 1,179,648
#define NW2 (H*II)     // Wo elems  1,769,472

typedef __attribute__((ext_vector_type(8))) short short8;
typedef __attribute__((ext_vector_type(4))) float f32x4;

__device__ __forceinline__ float b2f(ushort u){
  union { float f; unsigned int u; } v; v.u = ((unsigned int)u) << 16; return v.f;
}
__device__ __forceinline__ ushort f2b(float f){
  union { float f; unsigned int u; } v; v.f = f;
  unsigned int u = v.u;
  return (ushort)((u + 0x7fffu + ((u >> 16) & 1u)) >> 16);
}
__device__ __forceinline__ float gelu_f(float x){
  return 0.5f * x * (1.0f + erff(x * 0.70710678118654752f));
}
// async global(16B/lane) -> LDS (wave-uniform base + lane*16)
__device__ __forceinline__ void async_copy16(const ushort* g, ushort* l){
  __builtin_amdgcn_global_load_lds(
      (const __attribute__((address_space(1))) void*)g,
      (__attribute__((address_space(3))) void*)l, 16, 0, 0);
}

// ---- block-wide sum of two floats across 256 threads (4 waves) ----
__device__ __forceinline__ void block_sum2(float& s, float& s2, float* red, int t){
  #pragma unroll
  for(int off=32; off>=1; off>>=1){ s += __shfl_xor(s, off); s2 += __shfl_xor(s2, off); }
  int w = t >> 6;
  if((t & 63) == 0){ red[w] = s; red[4 + w] = s2; }
  __syncthreads();
  s  = red[0] + red[1] + red[2] + red[3];
  s2 = red[4] + red[5] + red[6] + red[7];
}

// ---- fused f32->bf16 convert of Wv|Wqk|Wo into one contiguous bf16 buffer ----
__global__ __launch_bounds__(256)
void f2b3_kernel(const float* __restrict__ in0, const float* __restrict__ in1,
                 const float* __restrict__ in2, ushort* __restrict__ out){
  int i = (blockIdx.x * 256 + threadIdx.x) * 4;
  const float* src; int off;
  if(i < NW0){ src = in0; off = i; }
  else if(i < NW0+NW1){ src = in1; off = i - NW0; }
  else { src = in2; off = i - NW0 - NW1; }
  float4 v = *(const float4*)(src + off);
  __attribute__((aligned(8))) ushort tmp[4] = { f2b(v.x), f2b(v.y), f2b(v.z), f2b(v.w) };
  *(uint2*)(out + i) = *(const uint2*)tmp;
}

// ---- x = LN(word_emb[ids])  (f32 in, f32 out) ----
__global__ __launch_bounds__(256)
void embed_ln_kernel(const int* __restrict__ ids, const float* __restrict__ wemb,
                     float* __restrict__ x)
{
  __shared__ float red[8];
  const int sb = blockIdx.x, t = threadIdx.x;
  const float* row = wemb + (size_t)ids[sb] * H;
  float v0 = row[t], v1 = row[t+256], v2 = row[t+512];
  float s = v0+v1+v2, s2 = v0*v0+v1*v1+v2*v2;
  block_sum2(s, s2, red, t);
  float mean = s * (1.0f/H);
  float rstd = rsqrtf(s2*(1.0f/H) - mean*mean + EPS);
  float* xo = x + (size_t)sb * H;
  xo[t]     = (v0-mean)*rstd;
  xo[t+256] = (v1-mean)*rstd;
  xo[t+512] = (v2-mean)*rstd;
}

// ---- relb = LN(rel_emb)*w + b  (f32 in, bf16 out) ----
__global__ __launch_bounds__(256)
void rel_ln_kernel(const float* __restrict__ rel_emb, const float* __restrict__ w,
                   const float* __restrict__ bia, ushort* __restrict__ outb)
{
  __shared__ float red[8];
  const int j = blockIdx.x, t = threadIdx.x;
  const float* row = rel_emb + (size_t)j * H;
  float v0=row[t], v1=row[t+256], v2=row[t+512];
  float s=v0+v1+v2, s2=v0*v0+v1*v1+v2*v2;
  block_sum2(s,s2,red,t);
  float mean = s*(1.0f/H);
  float rstd = rsqrtf(s2*(1.0f/H)-mean*mean+EPS);
  ushort* o = outb + (size_t)j*H;
  o[t]     = f2b((v0-mean)*rstd * w[t]     + bia[t]);
  o[t+256] = f2b((v1-mean)*rstd * w[t+256] + bia[t+256]);
  o[t+512] = f2b((v2-mean)*rstd * w[t+512] + bia[t+512]);
}

// ---- h = LN(x)  (bf16 out) ----
__global__ __launch_bounds__(256)
void ln_x_kernel(const float* __restrict__ x, ushort* __restrict__ h)
{
  __shared__ float red[8];
  const int sb = blockIdx.x, t = threadIdx.x;
  const float* row = x + (size_t)sb * H;
  float v0 = row[t], v1 = row[t+256], v2 = row[t+512];
  float s = v0+v1+v2, s2 = v0*v0+v1*v1+v2*v2;
  block_sum2(s, s2, red, t);
  float mean = s * (1.0f/H);
  float rstd = rsqrtf(s2*(1.0f/H) - mean*mean + EPS);
  ushort* o = h + (size_t)sb * H;
  o[t]     = f2b((v0-mean)*rstd);
  o[t+256] = f2b((v1-mean)*rstd);
  o[t+512] = f2b((v2-mean)*rstd);
}

// ---- bucket table: pidx depends only on (q-k); sample row 0 / row 511 ----
__global__ __launch_bounds__(256)
void bucket_kernel(const int* __restrict__ pidx, unsigned char* __restrict__ buk){
  int r = blockIdx.x*256 + threadIdx.x;   // [0,1024)
  int rel = r - 511;
  int v = 0;
  if(rel <= 0)          v = pidx[-rel];               // row 0, col -rel
  else if(rel <= 511)   v = pidx[511*S + (511-rel)];  // row 511
  buk[r] = (unsigned char)v;
}

// ---- small GEMM (64x64 tile): pos = relb @ Wqk^T + bqk (M=63) ----
__global__ __launch_bounds__(256)
void gemm_nt64(const ushort* __restrict__ A, const ushort* __restrict__ Bw,
               const float* __restrict__ bias, ushort* __restrict__ Cout,
               int M, int N, int K)
{
  __shared__ ushort As[64][40];
  __shared__ ushort Bs[64][40];
  const int n0 = blockIdx.x * 64, m0 = blockIdx.y * 64;
  const int t = threadIdx.x;
  const int lrow = t >> 2, lk = (t & 3) * 8;
  const int lane = t & 63, w = t >> 6, lr = lane & 15, lq = lane >> 4;
  const int wr = (w >> 1) * 32, wc = (w & 1) * 32;
  f32x4 z = {0.f,0.f,0.f,0.f};
  f32x4 acc[2][2] = {{z,z},{z,z}};
  const int arow = m0 + lrow;
  const ushort* aptr = A  + (size_t)arow * K + lk;
  const ushort* bptr = Bw + (size_t)(n0 + lrow) * K + lk;
  for(int k0 = 0; k0 < K; k0 += 32){
    short8 av = {0,0,0,0,0,0,0,0};
    if(arow < M) av = *(const short8*)(aptr + k0);
    short8 bv = *(const short8*)(bptr + k0);
    __syncthreads();
    *(short8*)&As[lrow][lk] = av;
    *(short8*)&Bs[lrow][lk] = bv;
    __syncthreads();
    short8 a0 = *(const short8*)&As[wr + lr][lq * 8];
    short8 a1 = *(const short8*)&As[wr + 16 + lr][lq * 8];
    short8 b0 = *(const short8*)&Bs[wc + lr][lq * 8];
    short8 b1 = *(const short8*)&Bs[wc + 16 + lr][lq * 8];
    acc[0][0] = __builtin_amdgcn_mfma_f32_16x16x32_bf16(a0, b0, acc[0][0], 0,0,0);
    acc[0][1] = __builtin_amdgcn_mfma_f32_16x16x32_bf16(a0, b1, acc[0][1], 0,0,0);
    acc[1][0] = __builtin_amdgcn_mfma_f32_16x16x32_bf16(a1, b0, acc[1][0], 0,0,0);
    acc[1][1] = __builtin_amdgcn_mfma_f32_16x16x32_bf16(a1, b1, acc[1][1], 0,0,0);
  }
  #pragma unroll
  for(int i=0;i<2;i++){
    #pragma unroll
    for(int j=0;j<2;j++){
      #pragma unroll
      for(int r=0;r<4;r++){
        int m = m0 + wr + i*16 + lq*4 + r;
        int n = n0 + wc + j*16 + lr;
        if(m >= M) continue;
        float v = acc[i][j][r];
        if(bias) v += bias[n];
        Cout[(size_t)m*N + n] = f2b(v);
      }
    }
  }
}

// ---- shared K-loop building blocks: 128x128 tile, 256 thr, BK=64, double
// buffer, depth-1 prefetch with PINNED ISSUE: the sched_barrier(0) right
// after the stage group stops the scheduler from sinking the gload_lds
// toward the consuming barrier (r9 lesson: unfenced, the prefetch issue
// drifts late and every K-tile exposes full HBM latency -> MfmaUtil pinned
// at 19% across 4 structural variants). Below the fence, ds_read+MFMA stay
// unfenced so the compiler's counted lgkmcnt interleaves them. ----
#define VGQK9_STAGE(KT, SA, SB) do {                                           \
    const int k0_ = (KT)*64;                                                   \
    async_copy16(aSrc + k0_,                 (SA) + dA);                       \
    async_copy16(aSrc + (size_t)32*K + k0_,  (SA) + 2048  + dA);               \
    async_copy16(aSrc + (size_t)64*K + k0_,  (SA) + 4096  + dA);               \
    async_copy16(aSrc + (size_t)96*K + k0_,  (SA) + 6144  + dA);               \
    async_copy16(bSrc + k0_,                 (SB) + dA);                       \
    async_copy16(bSrc + (size_t)32*K + k0_,  (SB) + 2048  + dA);               \
    async_copy16(bSrc + (size_t)64*K + k0_,  (SB) + 4096  + dA);               \
    async_copy16(bSrc + (size_t)96*K + k0_,  (SB) + 6144  + dA);               \
  } while(0)

#define VGQK9_TILE(KT, CA, CB, SA, SB) do {                                    \
    __syncthreads();                                                           \
    if((KT)+1 < NT) VGQK9_STAGE((KT)+1, SA, SB);                               \
    __builtin_amdgcn_sched_barrier(0);  /* pin prefetch issue at tile top */   \
    short8 af_[4][2], bf_[4][2];                                               \
    _Pragma("unroll")                                                          \
    for(int i=0;i<4;i++)                                                       \
      _Pragma("unroll")                                                        \
      for(int ks=0;ks<2;ks++)                                                  \
        af_[i][ks] = *(const short8*)&(CA)[(wr + i*16 + lr)*64 + ((ks*32 + lq*8) ^ rxor)]; \
    _Pragma("unroll")                                                          \
    for(int j=0;j<4;j++)                                                       \
      _Pragma("unroll")                                                        \
      for(int ks=0;ks<2;ks++)                                                  \
        bf_[j][ks] = *(const short8*)&(CB)[(wc + j*16 + lr)*64 + ((ks*32 + lq*8) ^ rxor)]; \
    _Pragma("unroll")                                                          \
    for(int i=0;i<4;i++)                                                       \
      _Pragma("unroll")                                                        \
      for(int j=0;j<4;j++)                                                     \
        _Pragma("unroll")                                                      \
        for(int ks=0;ks<2;ks++)                                                \
          acc[i][j] = __builtin_amdgcn_mfma_f32_16x16x32_bf16(af_[i][ks], bf_[j][ks], acc[i][j], 0,0,0); \
  } while(0)

// ---- main GEMM v2: pipelined 128x128, runtime K (multiple of 128) ----
// OUT_MODE: 0 = f32 store, 1 = bf16 store, 2 = f32 accumulate (+=)
template<int OUT_MODE>
__global__ __launch_bounds__(256)
void gemm128p(const ushort* __restrict__ A, const ushort* __restrict__ Bw,
              const float* __restrict__ bias, void* __restrict__ Cout,
              int M, int N, int K)
{
  const int NT = K / 64;   // even (K multiple of 128)
  __shared__ ushort As0[8192];
  __shared__ ushort Bs0[8192];
  __shared__ ushort As1[8192];
  __shared__ ushort Bs1[8192];
  const int t = threadIdx.x;
  const int w = t >> 6, l = t & 63, lr = l & 15, lq = l >> 4;
  const int wr = (w >> 1) * 64, wc = (w & 1) * 64;
  const int m0 = blockIdx.y*128, n0 = blockIdx.x*128;

  const int srow = t >> 3;
  const int scol = ((t & 7) ^ (srow & 7)) << 3;  // pre-swizzled source col
  const ushort* aSrc = A  + (size_t)(m0 + srow) * K + scol;
  const ushort* bSrc = Bw + (size_t)(n0 + srow) * K + scol;
  const int dA = w * 512;
  const int rxor = (lr & 7) << 3;

  f32x4 z = {0.f,0.f,0.f,0.f};
  f32x4 acc[4][4] = {{z,z,z,z},{z,z,z,z},{z,z,z,z},{z,z,z,z}};

  VGQK9_STAGE(0, As0, Bs0);
  for(int m2 = 0; m2 < NT/2; m2++){
    const int kt = 2*m2;
    VGQK9_TILE(kt,   As0, Bs0, As1, Bs1);
    VGQK9_TILE(kt+1, As1, Bs1, As0, Bs0);
  }

  #pragma unroll
  for(int i=0;i<4;i++){
    #pragma unroll
    for(int j=0;j<4;j++){
      #pragma unroll
      for(int r=0;r<4;r++){
        int m = m0 + wr + i*16 + lq*4 + r;
        int n = n0 + wc + j*16 + lr;
        float v = acc[i][j][r];
        if(bias) v += bias[n];
        if(OUT_MODE == 0)      ((float*) Cout)[(size_t)m*N + n] = v;
        else if(OUT_MODE == 1) ((ushort*)Cout)[(size_t)m*N + n] = f2b(v);
        else                   ((float*) Cout)[(size_t)m*N + n] += v;
      }
    }
  }
}

// ---- vg+qk GEMM v9 + pinned prefetch issue ----
__global__ __launch_bounds__(256)
void gemm_vgqk9(const ushort* __restrict__ A, const ushort* __restrict__ Ww,
                const float* __restrict__ bqk, ushort* __restrict__ vg,
                ushort* __restrict__ qk)
{
  constexpr int K  = H;        // 768
  constexpr int NT = K / 64;   // 12 k-tiles (even)
  __shared__ ushort As0[8192];
  __shared__ ushort Bs0[8192];
  __shared__ ushort As1[8192];
  __shared__ ushort Bs1[8192];
  const int t = threadIdx.x;
  const int w = t >> 6, l = t & 63, lr = l & 15, lq = l >> 4;
  const int wr = (w >> 1) * 64, wc = (w & 1) * 64;
  // bijective XCD swizzle: 1536 blocks = 8 XCDs x 192; chunk = 6 B-panels x 32 m
  int id = blockIdx.x;
  int swz = (id & 7) * 192 + (id >> 3);
  const int bm = swz & 31, bn = swz >> 5;     // 32 m-blocks, 48 n-blocks
  const int m0 = bm * 128, n0 = bn * 128;

  const int srow = t >> 3;
  const int scol = ((t & 7) ^ (srow & 7)) << 3;  // ushort units
  const ushort* aSrc = A  + (size_t)(m0 + srow) * K + scol;
  const ushort* bSrc = Ww + (size_t)(n0 + srow) * K + scol;
  const int dA = w * 512;
  const int rxor = (lr & 7) << 3;

  f32x4 z = {0.f,0.f,0.f,0.f};
  f32x4 acc[4][4] = {{z,z,z,z},{z,z,z,z},{z,z,z,z},{z,z,z,z}};

  VGQK9_STAGE(0, As0, Bs0);                   // prologue: tile 0 -> buf0

  for(int m2 = 0; m2 < NT/2; m2++){
    const int kt = 2*m2;
    VGQK9_TILE(kt,   As0, Bs0, As1, Bs1);
    VGQK9_TILE(kt+1, As1, Bs1, As0, Bs0);
  }

  const bool is_qk = (n0 >= 2*II);
  #pragma unroll
  for(int i=0;i<4;i++){
    #pragma unroll
    for(int j=0;j<4;j++){
      #pragma unroll
      for(int r=0;r<4;r++){
        int m = m0 + wr + i*16 + lq*4 + r;
        int n = n0 + wc + j*16 + lr;
        float v = acc[i][j][r];
        if(is_qk){
          int nq = n - 2*II;
          qk[(size_t)m*(2*H) + nq] = f2b(v + bqk[nq]);
        } else {
          vg[(size_t)m*(2*II) + n] = f2b(v);
        }
      }
    }
  }
}

// ---- merged: Vt transpose (blocks [0,1536)) + cp/cq MFMA ([1536,2304))
//      + K transpose ([2304,2400)): kT[bh][s][64] for coalesced attn K reads ----
__global__ __launch_bounds__(256)
void vtcpq_kernel(const ushort* __restrict__ vg, ushort* __restrict__ vt,
                  const ushort* __restrict__ qk, const ushort* __restrict__ posb,
                  ushort* __restrict__ cpT, ushort* __restrict__ cqT,
                  ushort* __restrict__ kT)
{
  const int id = blockIdx.x;
  const int t = threadIdx.x;
  __shared__ ushort tile[32][200];
  if(id < 1536){
    const int st = id & 15;
    const int hh = (id >> 4) % 12;
    const int b  = id / 192;
    {
      int sl = t >> 3, v0 = (t & 7) * 24;
      const ushort* src = vg + ((size_t)((st*32 + sl)*B + b))*(2*II) + hh*DV + v0;
      *(short8*)&tile[sl][v0]      = *(const short8*)(src);
      *(short8*)&tile[sl][v0 + 8]  = *(const short8*)(src + 8);
      *(short8*)&tile[sl][v0 + 16] = *(const short8*)(src + 16);
    }
    __syncthreads();
    if(t < DV){
      __attribute__((aligned(16))) ushort tmp[32];
      #pragma unroll
      for(int s2=0;s2<32;s2++) tmp[s2] = tile[s2][t];
      // k-slab-major layout: vt[((bh*16 + st)*DV + v)*32 + c]  (fully coalesced)
      ushort* dst = vt + ((((size_t)(b*NH + hh))*16 + st)*DV + t)*32;
      #pragma unroll
      for(int c=0;c<32;c+=8) *(short8*)(dst + c) = *(const short8*)&tmp[c];
    }
  } else if(id < 2304){
    const int jid = id - 1536;
    const int kc = jid & 3;
    const int bh = (jid >> 2) % 96;
    const int which = jid / 384;
    const int bb = bh / NH, h = bh - bb*NH;
    const int w = t>>6, lane = t&63, lr = lane&15, lq = lane>>4;
    const ushort* ab = posb + (size_t)(w*16 + lr)*1536 + (which ? 0 : 768) + h*64;
    short8 a0 = *(const short8*)(ab + lq*8);
    short8 a1 = *(const short8*)(ab + 32 + lq*8);
    f32x4 z = {0.f,0.f,0.f,0.f};
    f32x4 acc[8] = {z,z,z,z,z,z,z,z};
    #pragma unroll
    for(int nt=0; nt<8; nt++){
      const int k = kc*128 + nt*16 + lr;
      const ushort* bp = qk + ((size_t)k*B + bb)*1536 + (which ? 768 : 0) + h*64;
      short8 b0 = *(const short8*)(bp + lq*8);
      short8 b1 = *(const short8*)(bp + 32 + lq*8);
      acc[nt] = __builtin_amdgcn_mfma_f32_16x16x32_bf16(a0, b0, acc[nt], 0,0,0);
      acc[nt] = __builtin_amdgcn_mfma_f32_16x16x32_bf16(a1, b1, acc[nt], 0,0,0);
    }
    ushort* outp = which ? cqT : cpT;
    #pragma unroll
    for(int nt=0; nt<8; nt++){
      #pragma unroll
      for(int r=0;r<4;r++){
        int j = w*16 + lq*4 + r;
        int k = kc*128 + nt*16 + lr;
        outp[((size_t)bh*64 + j)*512 + k] = f2b(acc[nt][r]);
      }
    }
  } else {
    // K transpose: qk K-half [s][b][hh*64+d] -> kT[(bh*512 + s)*64 + d]
    const int id2 = id - 2304;                 // [0,96)
    const int bb = id2 / NH, hh = id2 - bb*NH;
    const int sl = t >> 3, d0 = (t & 7) * 8;
    const ushort* srcb = qk + (size_t)bb*1536 + H + hh*64 + d0;
    ushort* dstb = kT + ((size_t)id2*512 + sl)*64 + d0;
    #pragma unroll
    for(int i=0;i<16;i++){
      int s = i*32 + sl;
      *(short8*)(dstb + (size_t)i*32*64) = *(const short8*)(srcb + (size_t)s*B*1536);
    }
  }
}

// ---- fused attention, 32 q-rows per block; grid (bh=96, qt=16) ----
__global__ __launch_bounds__(256)
void attn_kernel(const ushort* __restrict__ qk, const ushort* __restrict__ vt,
                 const ushort* __restrict__ kT,
                 const ushort* __restrict__ cpT, const ushort* __restrict__ cqT,
                 const unsigned char* __restrict__ bukg, ushort* __restrict__ ctx)
{
  const int bh = blockIdx.x, qt = blockIdx.y;
  const int b = bh / NH, hh = bh - b*NH;
  __shared__ ushort Qs[32][72];            //  4,608 B
  __shared__ float  cps[32][65];           //  8,320 B
  __shared__ ushort cqslab[32*520];        // 33,280 B; cq-gather early, Ps late
  __shared__ unsigned char bukl[1024];
  __shared__ float redm[4][32];
  __shared__ float reds[4][32];
  __shared__ float rowinv[32];
  const int t = threadIdx.x, w = t>>6, lane = t&63, lr = lane&15, lq = lane>>4;

  ((uint*)bukl)[t] = ((const uint*)bukg)[t & 255];
  for(int i=t; i<512; i+=256){
    int r = i >> 4, d0 = (i & 15) * 4;
    const ushort* src = qk + ((size_t)((qt*32 + r)*B + b))*1536 + hh*DH + d0;
    *(uint2*)&Qs[r][d0] = *(const uint2*)src;
  }
  for(int i=t; i<32*64; i+=256){
    int j = i >> 5, r = i & 31;
    cps[r][j] = b2f(cpT[((size_t)bh*64 + j)*512 + qt*32 + r]);
  }
  __syncthreads();   // bukl visible for the cq staging below

  // ---- cq staging: cqslab[q][k] = cqT[bh][pi(q,k)][k] ----
  const ushort* cqbase = cqT + (size_t)bh*64*512;
  #pragma unroll 8
  for(int n=0; n<64; n++){
    int i = n*256 + t;
    int k = i & 511, q = i >> 9;
    int pi = (int)bukl[(qt*32 + q) - k + 511];
    cqslab[q*520 + k] = cqbase[(size_t)pi*512 + k];
  }
  __syncthreads();

  short8 a00 = *(const short8*)&Qs[lr][lq*8];
  short8 a01 = *(const short8*)&Qs[lr][32 + lq*8];
  short8 a10 = *(const short8*)&Qs[16 + lr][lq*8];
  short8 a11 = *(const short8*)&Qs[16 + lr][32 + lq*8];

  float sc[8][8];
  const int kbase = w * 128;
  const ushort* ktb = kT + (size_t)bh*512*64;
  f32x4 z4 = {0.f,0.f,0.f,0.f};
  #pragma unroll
  for(int tile=0; tile<8; tile++){
    const int k0 = kbase + tile*16;
    const ushort* kp = ktb + (size_t)(k0 + lr)*64 + lq*8;   // dense 2KB strip
    short8 b0 = *(const short8*)kp;
    short8 b1 = *(const short8*)(kp + 32);
    f32x4 acc[2] = {z4, z4};
    acc[0] = __builtin_amdgcn_mfma_f32_16x16x32_bf16(a00, b0, acc[0], 0,0,0);
    acc[0] = __builtin_amdgcn_mfma_f32_16x16x32_bf16(a01, b1, acc[0], 0,0,0);
    acc[1] = __builtin_amdgcn_mfma_f32_16x16x32_bf16(a10, b0, acc[1], 0,0,0);
    acc[1] = __builtin_amdgcn_mfma_f32_16x16x32_bf16(a11, b1, acc[1], 0,0,0);
    const int kcol = k0 + lr;
    #pragma unroll
    for(int qs=0;qs<2;qs++){
      #pragma unroll
      for(int r=0;r<4;r++){
        int ql = qs*16 + lq*4 + r;
        int pi = (int)bukl[(qt*32 + ql) - kcol + 511];
        sc[tile][qs*4+r] = (acc[qs][r] + cps[ql][pi]
                       + b2f(cqslab[ql*520 + kcol])) * SCALE;
      }
    }
  }

  float gm[8];
  #pragma unroll
  for(int j=0;j<8;j++){
    float m = sc[0][j];
    #pragma unroll
    for(int tile=1;tile<8;tile++) m = fmaxf(m, sc[tile][j]);
    #pragma unroll
    for(int off=1; off<16; off<<=1) m = fmaxf(m, __shfl_xor(m, off));
    if(lr==0) redm[w][(j>>2)*16 + lq*4 + (j&3)] = m;
  }
  __syncthreads();
  #pragma unroll
  for(int j=0;j<8;j++){
    int ql = (j>>2)*16 + lq*4 + (j&3);
    gm[j] = fmaxf(fmaxf(redm[0][ql],redm[1][ql]),fmaxf(redm[2][ql],redm[3][ql]));
  }
  #pragma unroll
  for(int j=0;j<8;j++){
    float s = 0.f;
    #pragma unroll
    for(int tile=0;tile<8;tile++){ float e = __expf(sc[tile][j]-gm[j]); sc[tile][j]=e; s+=e; }
    #pragma unroll
    for(int off=1; off<16; off<<=1) s += __shfl_xor(s, off);
    if(lr==0) reds[w][(j>>2)*16 + lq*4 + (j&3)] = s;
  }
  __syncthreads();            // last cqslab read was 2 barriers ago -> alias Ps
  #pragma unroll
  for(int j=0;j<8;j++){
    int ql = (j>>2)*16 + lq*4 + (j&3);
    float g = reds[0][ql]+reds[1][ql]+reds[2][ql]+reds[3][ql];
    if(w==0 && lr==0) rowinv[ql] = 1.0f/g;
  }
  ushort* Psp = cqslab;        // Ps[32][520] aliases the cq slab
  #pragma unroll
  for(int tile=0;tile<8;tile++){
    #pragma unroll
    for(int j=0;j<8;j++){
      int ql = (j>>2)*16 + lq*4 + (j&3);
      Psp[ql*520 + kbase + tile*16 + lr] = f2b(sc[tile][j]);
    }
  }
  __syncthreads();

  f32x4 acc2[2][3] = {{z4,z4,z4},{z4,z4,z4}};
  const ushort* vbh = vt + (size_t)bh*16*DV*32;
  #pragma unroll 4
  for(int kk=0; kk<S; kk+=32){
    short8 p0 = *(const short8*)&Psp[lr*520 + kk + lq*8];
    short8 p1 = *(const short8*)&Psp[(16 + lr)*520 + kk + lq*8];
    const ushort* vslab = vbh + (size_t)(kk>>5)*DV*32;
    #pragma unroll
    for(int ti=0; ti<3; ti++){
      const int v0 = (w*3 + ti)*16;
      short8 bv = *(const short8*)(vslab + (size_t)(v0 + lr)*32 + lq*8);  // dense 1KB strip
      acc2[0][ti] = __builtin_amdgcn_mfma_f32_16x16x32_bf16(p0, bv, acc2[0][ti], 0,0,0);
      acc2[1][ti] = __builtin_amdgcn_mfma_f32_16x16x32_bf16(p1, bv, acc2[1][ti], 0,0,0);
    }
  }
  #pragma unroll
  for(int qs=0;qs<2;qs++){
    #pragma unroll
    for(int ti=0; ti<3; ti++){
      const int v0 = (w*3 + ti)*16;
      #pragma unroll
      for(int r=0;r<4;r++){
        int ql = qs*16 + lq*4 + r;
        float val = acc2[qs][ti][r] * rowinv[ql];
        ctx[((size_t)((qt*32+ql)*B + b))*II + hh*DV + v0 + lr] = f2b(val);
      }
    }
  }
}

// ---- ctx2 = LN( (ctx + sigmoid(lskip)*gelu(value)) * gelu(gate) )  (bf16) ----
__global__ __launch_bounds__(256)
void glu_ln_kernel(const ushort* __restrict__ ctx, const ushort* __restrict__ vg,
                   const float* __restrict__ ls, ushort* __restrict__ outb)
{
  __shared__ float red[8];
  const int sb = blockIdx.x, t = threadIdx.x;
  const ushort* crow = ctx + (size_t)sb*II;
  const ushort* vrow = vg + (size_t)sb*2*II;
  float c[9]; float s=0.f, s2=0.f;
  #pragma unroll
  for(int i=0;i<9;i++){
    int idx = t + i*256;
    float cv  = b2f(crow[idx]);
    float val = b2f(vrow[idx]);
    float gt  = b2f(vrow[II + idx]);
    float sk  = 1.0f/(1.0f + __expf(-ls[idx]));
    cv = (cv + sk*gelu_f(val)) * gelu_f(gt);
    c[i]=cv; s+=cv; s2+=cv*cv;
  }
  block_sum2(s,s2,red,t);
  float mean = s*(1.0f/II);
  float rstd = rsqrtf(s2*(1.0f/II)-mean*mean+EPS);
  ushort* o = outb + (size_t)sb*II;
  #pragma unroll
  for(int i=0;i<9;i++) o[t+i*256] = f2b((c[i]-mean)*rstd);
}

// ---- final copy x(f32) -> out(f32) ----
__global__ __launch_bounds__(256)
void copy_kernel(const float* __restrict__ x, float* __restrict__ out){
  int i = (blockIdx.x*256 + threadIdx.x)*4;
  *(float4*)(out + i) = *(const float4*)(x + i);
}

extern "C" void kernel_launch(void* const* d_in, const int* in_sizes, int n_in,
                              void* d_out, int out_size, void* d_ws, size_t ws_size,
                              hipStream_t stream)
{
  (void)in_sizes; (void)n_in; (void)out_size; (void)ws_size;
  const int* ids      = (const int*)d_in[0];
  const int* pidx     = (const int*)d_in[2];
  const float* wemb   = (const float*)d_in[3];
  const float* rele   = (const float*)d_in[4];
  const float* rlw    = (const float*)d_in[5];
  const float* rlb    = (const float*)d_in[6];
  const float* Wv     = (const float*)d_in[7];
  const float* Wqk    = (const float*)d_in[8];
  const float* bqk    = (const float*)d_in[9];
  const float* Wo     = (const float*)d_in[10];
  const float* lskip  = (const float*)d_in[11];

  char* wsb = (char*)d_ws;
  float*  x     = (float*) (wsb + 0);           // 12,582,912 B
  ushort* h     = (ushort*)(wsb + 12582912);    //  6,291,456
  ushort* relb  = (ushort*)(wsb + 18874368);    //     98,304
  ushort* posb  = (ushort*)(wsb + 18972672);    //    196,608 (63 rows used of 64)
  ushort* vg    = (ushort*)(wsb + 19169280);    // 37,748,736
  ushort* qk    = (ushort*)(wsb + 56918016);    // 12,582,912
  ushort* cpT   = (ushort*)(wsb + 69500928);    //  6,291,456 (bf16 [96][64][512])
  ushort* cqT   = (ushort*)(wsb + 75792384);    //  6,291,456
  ushort* ctx   = (ushort*)(wsb + 82083840);    // 18,874,368
  ushort* vt    = (ushort*)(wsb + 100958208);   // 18,874,368 (k-slab-major layout)
  ushort* ctxln = vt;                           // alias: disjoint live ranges
  ushort* wvqk  = (ushort*)(wsb + 119832576);   // [Wv;Wqk;Wo] bf16 contiguous: 12,976,128
  ushort* wqkb  = wvqk + (size_t)NW0;
  ushort* wob   = wvqk + (size_t)(NW0 + NW1);   // ends ~132.8 MB
  // kT aliases h: h is dead after gemm_vgqk9 consumes it; vtcpq writes kT,
  // attn reads it, next layer's ln_x rewrites h afterward. Exact size match.
  ushort* kT    = h;                            // [96][512][64] bf16 = 6,291,456 B
  // bucket table lives in posb's unused 64th row (rows >= 63 never written)
  unsigned char* bukg = (unsigned char*)(posb + 63*1536);  // 1,024 B of 3,072 spare

  embed_ln_kernel<<<S*B, 256, 0, stream>>>(ids, wemb, x);
  rel_ln_kernel<<<63, 256, 0, stream>>>(rele, rlw, rlb, relb);
  bucket_kernel<<<4, 256, 0, stream>>>(pidx, bukg);

  for(int l=0; l<NL; l++){
    const float* Wv_l  = Wv  + (size_t)l * NW0;
    const float* Wqk_l = Wqk + (size_t)l * NW1;
    const float* bqk_l = bqk + (size_t)l * (2*H);
    const float* Wo_l  = Wo  + (size_t)l * NW2;
    const float* ls_l  = lskip + (size_t)l * II;

    f2b3_kernel<<<(NW0+NW1+NW2)/1024, 256, 0, stream>>>(Wv_l, Wqk_l, Wo_l, wvqk);
    ln_x_kernel<<<S*B, 256, 0, stream>>>(x, h);
    gemm_nt64<<<dim3((2*H)/64, 1), 256, 0, stream>>>(relb, wqkb, bqk_l, posb, 63, 2*H, H);
    gemm_vgqk9<<<1536, 256, 0, stream>>>(h, wvqk, bqk_l, vg, qk);
    vtcpq_kernel<<<2400, 256, 0, stream>>>(vg, vt, qk, posb, cpT, cqT, kT);
    attn_kernel<<<dim3(B*NH, S/32), 256, 0, stream>>>(qk, vt, kT, cpT, cqT, bukg, ctx);
    glu_ln_kernel<<<S*B, 256, 0, stream>>>(ctx, vg, ls_l, ctxln);
    gemm128p<2><<<dim3(H/128, (S*B)/128), 256, 0, stream>>>(ctxln, wob, nullptr, x, S*B, H, II);
  }
  copy_kernel<<<(S*B*H)/1024, 256, 0, stream>>>(x, (float*)d_out);
}